// Round 6
// baseline (296.347 us; speedup 1.0000x reference)
//
#include <hip/hip_runtime.h>

#define IN_DIM 128
#define HID_DIM 128
#define OUT_DIM 64

typedef short bf16x8 __attribute__((ext_vector_type(8)));   // 8 bf16 (4 VGPRs)
typedef float f32x4  __attribute__((ext_vector_type(4)));   // 4 fp32 acc

// ---- bf16 helpers (storage-only; math in fp32) ----
__device__ inline float bflo(unsigned int u) { return __uint_as_float(u << 16); }
__device__ inline float bfhi(unsigned int u) { return __uint_as_float(u & 0xffff0000u); }
__device__ inline unsigned short f2bf(float f) {
    unsigned int b = __float_as_uint(f);
    return (unsigned short)((b + 0x7FFFu + ((b >> 16) & 1u)) >> 16);  // RNE
}
__device__ inline unsigned int pack2(float a, float b) {
    return (unsigned int)f2bf(a) | ((unsigned int)f2bf(b) << 16);
}

// ===========================================================================
// CSR build step 1: histogram + per-edge rank (atomic return, ushort store).
// ===========================================================================
__global__ void hist_rank_kernel(const int* __restrict__ dst, int* __restrict__ cnt,
                                 unsigned short* __restrict__ rank, int E) {
    int e = blockIdx.x * blockDim.x + threadIdx.x;
    if (e < E) rank[e] = (unsigned short)atomicAdd(&cnt[dst[e]], 1);
}

__global__ void block_sums_kernel(const int* __restrict__ cnt, int* __restrict__ partial, int N) {
    __shared__ int s[256];
    int i = blockIdx.x * 256 + threadIdx.x;
    s[threadIdx.x] = (i < N) ? cnt[i] : 0;
    __syncthreads();
    for (int o = 128; o > 0; o >>= 1) {
        if (threadIdx.x < o) s[threadIdx.x] += s[threadIdx.x + o];
        __syncthreads();
    }
    if (threadIdx.x == 0) partial[blockIdx.x] = s[0];
}

__global__ void scan_partials_kernel(int* __restrict__ partial, int nB) {
    __shared__ int s[256];
    int v = (threadIdx.x < nB) ? partial[threadIdx.x] : 0;
    s[threadIdx.x] = v;
    __syncthreads();
    for (int o = 1; o < 256; o <<= 1) {
        int t = (threadIdx.x >= o) ? s[threadIdx.x - o] : 0;
        __syncthreads();
        s[threadIdx.x] += t;
        __syncthreads();
    }
    if (threadIdx.x < nB) partial[threadIdx.x] = s[threadIdx.x] - v;  // exclusive
}

__global__ void scan_chunks_kernel(const int* __restrict__ cnt, const int* __restrict__ partial,
                                   int* __restrict__ row_ptr, int N) {
    __shared__ int s[256];
    int i = blockIdx.x * 256 + threadIdx.x;
    int v = (i < N) ? cnt[i] : 0;
    s[threadIdx.x] = v;
    __syncthreads();
    for (int o = 1; o < 256; o <<= 1) {
        int t = (threadIdx.x >= o) ? s[threadIdx.x - o] : 0;
        __syncthreads();
        s[threadIdx.x] += t;
        __syncthreads();
    }
    int incl = s[threadIdx.x];
    int base = partial[blockIdx.x];
    if (i < N) row_ptr[i] = base + incl - v;
    if (i == N - 1) row_ptr[N] = base + incl;
}

// ===========================================================================
// Fused layer-1: blocks [0, FB) run the non-atomic CSR scatter (ushort);
// blocks [FB, FB+NGB) loop over MFMA dual-GEMM tiles (4 tiles/block).
// ===========================================================================
__global__ __launch_bounds__(256) void gemm1_fill_kernel(
        const float* __restrict__ x,
        const float* __restrict__ Wself,
        const float* __restrict__ Wneigh,
        const float* __restrict__ bias,
        float* __restrict__ hs,
        unsigned short* __restrict__ t,
        int N, int NT, int FB, int NGB,
        const int* __restrict__ src,
        const int* __restrict__ dst,
        const int* __restrict__ row_ptr,
        const unsigned short* __restrict__ rank,
        unsigned short* __restrict__ col_src,
        int E) {
    constexpr int DOUT = HID_DIM;
    constexpr int K   = 128;
    constexpr int MT  = 64;
    constexpr int WC  = 2 * DOUT;
    constexpr int SL  = WC / 4;      // 64
    constexpr int TN  = SL / 16;     // 4
    constexpr int TM  = MT / 16;     // 4
    constexpr int KS  = K / 32;      // 4
    constexpr int LDA = K + 8;

    __shared__ unsigned short sA[MT][LDA];

    const int tid = threadIdx.x;

    if ((int)blockIdx.x < FB) {
        int base = (int)blockIdx.x * 1024;
        #pragma unroll
        for (int k = 0; k < 4; ++k) {
            int e = base + k * 256 + tid;
            if (e < E) {
                int d = dst[e];
                col_src[row_ptr[d] + (int)rank[e]] = (unsigned short)src[e];
            }
        }
        return;
    }

    const int gb  = (int)blockIdx.x - FB;
    const int w   = tid >> 6;
    const int l   = tid & 63;
    const int l16 = l & 15;
    const int lhi = l >> 4;

    bf16x8 breg[TN][KS];
    float  bval[TN];
    #pragma unroll
    for (int tn = 0; tn < TN; ++tn) {
        const int c = w * SL + tn * 16 + l16;
        const bool self = (c < DOUT);
        const float* W = self ? &Wself[c] : &Wneigh[c - DOUT];
        bval[tn] = self ? bias[c] : 0.0f;
        #pragma unroll
        for (int ks = 0; ks < KS; ++ks) {
            const int k0 = ks * 32 + lhi * 8;
            bf16x8 f;
            #pragma unroll
            for (int j = 0; j < 8; ++j)
                f[j] = (short)f2bf(W[(size_t)(k0 + j) * DOUT]);
            breg[tn][ks] = f;
        }
    }

    for (int tile = gb; tile < NT; tile += NGB) {
        const int n0 = tile * MT;
        __syncthreads();
        #pragma unroll
        for (int it = 0; it < 8; ++it) {
            int flat = it * 256 + tid;
            int r  = flat >> 5;
            int c4 = flat & 31;
            float4 v = {0, 0, 0, 0};
            if (n0 + r < N) v = *(const float4*)&x[(size_t)(n0 + r) * K + c4 * 4];
            ushort4 p;
            p.x = f2bf(v.x); p.y = f2bf(v.y); p.z = f2bf(v.z); p.w = f2bf(v.w);
            *(ushort4*)&sA[r][c4 * 4] = p;
        }
        __syncthreads();

        f32x4 acc[TN][TM];
        #pragma unroll
        for (int tn = 0; tn < TN; ++tn)
            #pragma unroll
            for (int tm = 0; tm < TM; ++tm)
                acc[tn][tm] = (f32x4){0.0f, 0.0f, 0.0f, 0.0f};

        #pragma unroll
        for (int ks = 0; ks < KS; ++ks) {
            bf16x8 a[TM];
            #pragma unroll
            for (int tm = 0; tm < TM; ++tm)
                a[tm] = *(const bf16x8*)&sA[tm * 16 + l16][ks * 32 + lhi * 8];
            #pragma unroll
            for (int tn = 0; tn < TN; ++tn)
                #pragma unroll
                for (int tm = 0; tm < TM; ++tm)
                    acc[tn][tm] = __builtin_amdgcn_mfma_f32_16x16x32_bf16(
                        a[tm], breg[tn][ks], acc[tn][tm], 0, 0, 0);
        }

        #pragma unroll
        for (int tn = 0; tn < TN; ++tn) {
            const int c = w * SL + tn * 16 + l16;
            const bool self = (c < DOUT);
            const int cc = self ? c : c - DOUT;
            #pragma unroll
            for (int tm = 0; tm < TM; ++tm) {
                #pragma unroll
                for (int r = 0; r < 4; ++r) {
                    const int n = n0 + tm * 16 + lhi * 4 + r;
                    if (n < N) {
                        const float v = acc[tn][tm][r] + bval[tn];
                        if (self) hs[(size_t)n * DOUT + cc] = v;
                        else      t [(size_t)n * DOUT + cc] = f2bf(v);
                    }
                }
            }
        }
    }
}

// ===========================================================================
// Fused layer-2: gather-mean(t1) + relu(hs1 + mean) -> bf16 LDS A-tile ->
// MFMA dual GEMM -> hs2 (fp32), t2 (bf16). Eliminates the h1 global round trip.
// ===========================================================================
__global__ __launch_bounds__(256) void gather_gemm2_kernel(
        const unsigned short* __restrict__ t1,
        const float* __restrict__ hs1,
        const int* __restrict__ row_ptr,
        const unsigned short* __restrict__ col_src,
        const float* __restrict__ Wself,
        const float* __restrict__ Wneigh,
        const float* __restrict__ bias,
        float* __restrict__ hs2,
        unsigned short* __restrict__ t2,
        int N) {
    constexpr int DOUT = OUT_DIM;
    constexpr int K   = 128;
    constexpr int MT  = 64;
    constexpr int WC  = 2 * DOUT;    // 128
    constexpr int SL  = WC / 4;      // 32
    constexpr int TN  = SL / 16;     // 2
    constexpr int TM  = MT / 16;     // 4
    constexpr int KS  = K / 32;      // 4
    constexpr int LDA = K + 8;

    __shared__ unsigned short sA[MT][LDA];

    const int tid = threadIdx.x;
    const int w   = tid >> 6;
    const int l   = tid & 63;
    const int l16 = l & 15;
    const int lhi = l >> 4;

    bf16x8 breg[TN][KS];
    float  bval[TN];
    #pragma unroll
    for (int tn = 0; tn < TN; ++tn) {
        const int c = w * SL + tn * 16 + l16;
        const bool self = (c < DOUT);
        const float* W = self ? &Wself[c] : &Wneigh[c - DOUT];
        bval[tn] = self ? bias[c] : 0.0f;
        #pragma unroll
        for (int ks = 0; ks < KS; ++ks) {
            const int k0 = ks * 32 + lhi * 8;
            bf16x8 f;
            #pragma unroll
            for (int j = 0; j < 8; ++j)
                f[j] = (short)f2bf(W[(size_t)(k0 + j) * DOUT]);
            breg[tn][ks] = f;
        }
    }

    const int n0 = (int)blockIdx.x * MT;
    const int off = l * 2;

    for (int i = 0; i < 16; ++i) {
        const int r = w * 16 + i;
        const int node = n0 + r;
        if (node < N) {
            const int beg = row_ptr[node], end = row_ptr[node + 1];
            const float rdeg = 1.0f / fmaxf((float)(end - beg), 1.0f);
            float a0x = 0, a0y = 0, a1x = 0, a1y = 0, a2x = 0, a2y = 0, a3x = 0, a3y = 0;
            int j = beg;
            for (; j + 4 <= end; j += 4) {
                int s0 = col_src[j], s1 = col_src[j + 1], s2 = col_src[j + 2], s3 = col_src[j + 3];
                unsigned int u0 = *(const unsigned int*)&t1[(size_t)s0 * 128 + off];
                unsigned int u1 = *(const unsigned int*)&t1[(size_t)s1 * 128 + off];
                unsigned int u2 = *(const unsigned int*)&t1[(size_t)s2 * 128 + off];
                unsigned int u3 = *(const unsigned int*)&t1[(size_t)s3 * 128 + off];
                a0x += bflo(u0); a0y += bfhi(u0);
                a1x += bflo(u1); a1y += bfhi(u1);
                a2x += bflo(u2); a2y += bfhi(u2);
                a3x += bflo(u3); a3y += bfhi(u3);
            }
            for (; j < end; ++j) {
                unsigned int u = *(const unsigned int*)&t1[(size_t)col_src[j] * 128 + off];
                a0x += bflo(u); a0y += bfhi(u);
            }
            float ax = (a0x + a1x) + (a2x + a3x);
            float ay = (a0y + a1y) + (a2y + a3y);
            float2 b = *(const float2*)&hs1[(size_t)node * 128 + off];
            float hx = fmaxf(b.x + ax * rdeg, 0.0f);
            float hy = fmaxf(b.y + ay * rdeg, 0.0f);
            *(unsigned int*)&sA[r][off] = pack2(hx, hy);
        } else {
            *(unsigned int*)&sA[r][off] = 0;
        }
    }
    __syncthreads();

    f32x4 acc[TN][TM];
    #pragma unroll
    for (int tn = 0; tn < TN; ++tn)
        #pragma unroll
        for (int tm = 0; tm < TM; ++tm)
            acc[tn][tm] = (f32x4){0.0f, 0.0f, 0.0f, 0.0f};

    #pragma unroll
    for (int ks = 0; ks < KS; ++ks) {
        bf16x8 a[TM];
        #pragma unroll
        for (int tm = 0; tm < TM; ++tm)
            a[tm] = *(const bf16x8*)&sA[tm * 16 + l16][ks * 32 + lhi * 8];
        #pragma unroll
        for (int tn = 0; tn < TN; ++tn)
            #pragma unroll
            for (int tm = 0; tm < TM; ++tm)
                acc[tn][tm] = __builtin_amdgcn_mfma_f32_16x16x32_bf16(
                    a[tm], breg[tn][ks], acc[tn][tm], 0, 0, 0);
    }

    #pragma unroll
    for (int tn = 0; tn < TN; ++tn) {
        const int c = w * SL + tn * 16 + l16;
        const bool self = (c < DOUT);
        const int cc = self ? c : c - DOUT;
        #pragma unroll
        for (int tm = 0; tm < TM; ++tm) {
            #pragma unroll
            for (int r = 0; r < 4; ++r) {
                const int n = n0 + tm * 16 + lhi * 4 + r;
                if (n < N) {
                    const float v = acc[tn][tm][r] + bval[tn];
                    if (self) hs2[(size_t)n * DOUT + cc] = v;
                    else      t2 [(size_t)n * DOUT + cc] = f2bf(v);
                }
            }
        }
    }
}

// ===========================================================================
// Gather-mean layer 2 (D=64): 32 lanes per node (2 nodes/wave), bf16 out.
// ===========================================================================
__global__ void gather_mean64_kernel(const unsigned short* __restrict__ t,
                                     const float* __restrict__ base,
                                     const int* __restrict__ row_ptr,
                                     const unsigned short* __restrict__ col_src,
                                     unsigned short* __restrict__ out, int N) {
    int tid  = blockIdx.x * blockDim.x + threadIdx.x;
    int node = (tid >> 6) * 2 + ((tid >> 5) & 1);
    int m    = tid & 31;
    if (node >= N) return;
    const int beg = row_ptr[node], end = row_ptr[node + 1];
    const float rdeg = 1.0f / fmaxf((float)(end - beg), 1.0f);
    const int off = m * 2;

    float a0x = 0, a0y = 0, a1x = 0, a1y = 0, a2x = 0, a2y = 0, a3x = 0, a3y = 0;
    int i = beg;
    for (; i + 4 <= end; i += 4) {
        int s0 = col_src[i], s1 = col_src[i + 1], s2 = col_src[i + 2], s3 = col_src[i + 3];
        unsigned int u0 = *(const unsigned int*)&t[(size_t)s0 * 64 + off];
        unsigned int u1 = *(const unsigned int*)&t[(size_t)s1 * 64 + off];
        unsigned int u2 = *(const unsigned int*)&t[(size_t)s2 * 64 + off];
        unsigned int u3 = *(const unsigned int*)&t[(size_t)s3 * 64 + off];
        a0x += bflo(u0); a0y += bfhi(u0);
        a1x += bflo(u1); a1y += bfhi(u1);
        a2x += bflo(u2); a2y += bfhi(u2);
        a3x += bflo(u3); a3y += bfhi(u3);
    }
    for (; i < end; ++i) {
        unsigned int u = *(const unsigned int*)&t[(size_t)col_src[i] * 64 + off];
        a0x += bflo(u); a0y += bfhi(u);
    }
    float ax = (a0x + a1x) + (a2x + a3x);
    float ay = (a0y + a1y) + (a2y + a3y);
    float2 b = *(const float2*)&base[(size_t)node * 64 + off];
    *(unsigned int*)&out[(size_t)node * 64 + off] = pack2(b.x + ax * rdeg, b.y + ay * rdeg);
}

// ===========================================================================
// Edge dot on bf16 h (D=64, 128B rows): 8 lanes/edge, uint4 (8 bf16) loads.
// ===========================================================================
__global__ void edge_dot_kernel(const unsigned short* __restrict__ h,
                                const int* __restrict__ src,
                                const int* __restrict__ dst,
                                const int* __restrict__ nsrc,
                                const int* __restrict__ ndst,
                                float* __restrict__ out,
                                int E) {
    int tid = blockIdx.x * blockDim.x + threadIdx.x;
    int eg = tid >> 3;
    int l  = tid & 7;
    if (eg >= 2 * E) return;
    int s, t;
    if (eg < E) { s = src[eg];      t = dst[eg]; }
    else        { s = nsrc[eg - E]; t = ndst[eg - E]; }
    const uint4 a = *reinterpret_cast<const uint4*>(&h[(size_t)s * OUT_DIM + l * 8]);
    const uint4 b = *reinterpret_cast<const uint4*>(&h[(size_t)t * OUT_DIM + l * 8]);
    float v = bflo(a.x) * bflo(b.x) + bfhi(a.x) * bfhi(b.x)
            + bflo(a.y) * bflo(b.y) + bfhi(a.y) * bfhi(b.y)
            + bflo(a.z) * bflo(b.z) + bfhi(a.z) * bfhi(b.z)
            + bflo(a.w) * bflo(b.w) + bfhi(a.w) * bfhi(b.w);
    v += __shfl_xor(v, 4, 8);
    v += __shfl_xor(v, 2, 8);
    v += __shfl_xor(v, 1, 8);
    if (l == 0) out[eg] = v;
}

extern "C" void kernel_launch(void* const* d_in, const int* in_sizes, int n_in,
                              void* d_out, int out_size, void* d_ws, size_t ws_size,
                              hipStream_t stream) {
    const float* feat = (const float*)d_in[0];
    const float* Ws1  = (const float*)d_in[1];
    const float* Wn1  = (const float*)d_in[2];
    const float* b1   = (const float*)d_in[3];
    const float* Ws2  = (const float*)d_in[4];
    const float* Wn2  = (const float*)d_in[5];
    const float* b2   = (const float*)d_in[6];
    const int* src  = (const int*)d_in[7];
    const int* dst  = (const int*)d_in[8];
    const int* nsrc = (const int*)d_in[9];
    const int* ndst = (const int*)d_in[10];
    const int E = in_sizes[7];
    const int N = in_sizes[0] / IN_DIM;
    const int NB = (N + 255) / 256;
    const int NT = (N + 63) / 64;           // MFMA node tiles
    const int FB = (E + 1023) / 1024;       // scatter blocks
    const int NGB = (NT + 3) / 4;           // gemm blocks (4 tiles each)

    // ---- workspace layout ----
    int* wsi     = (int*)d_ws;
    int* cnt     = wsi;                  // N
    int* row_ptr = cnt + N;              // N+1
    int* partial = row_ptr + N + 1;      // 256
    unsigned short* rank    = (unsigned short*)(partial + 256);  // E
    unsigned short* col_src = rank + E;                          // E
    size_t int_count = (size_t)(2 * N + 1 + 256) + (size_t)E;    // 2*E ushorts = E ints
    int_count = (int_count + 3) & ~(size_t)3;
    unsigned short* t1 = (unsigned short*)(wsi + int_count);         // N*128 bf16
    float* hs1 = (float*)(t1 + (size_t)N * HID_DIM);                 // N*128 fp32
    unsigned short* t2 = (unsigned short*)(hs1 + (size_t)N * HID_DIM);  // N*64 bf16
    float* hs2 = (float*)(t2 + (size_t)N * OUT_DIM);                 // N*64 fp32
    unsigned short* h2 = (unsigned short*)(hs2 + (size_t)N * OUT_DIM);  // N*64 bf16

    // ---- CSR build: hist(+rank) -> scan ----
    hipMemsetAsync(cnt, 0, sizeof(int) * (size_t)N, stream);
    hist_rank_kernel<<<(E + 255) / 256, 256, 0, stream>>>(dst, cnt, rank, E);
    block_sums_kernel<<<NB, 256, 0, stream>>>(cnt, partial, N);
    scan_partials_kernel<<<1, 256, 0, stream>>>(partial, NB);
    scan_chunks_kernel<<<NB, 256, 0, stream>>>(cnt, partial, row_ptr, N);

    // ---- Layer 1 GEMM (multi-tile) fused with non-atomic CSR scatter ----
    gemm1_fill_kernel<<<FB + NGB, 256, 0, stream>>>(
        feat, Ws1, Wn1, b1, hs1, t1, N, NT, FB, NGB,
        src, dst, row_ptr, rank, col_src, E);

    // ---- Layer 2: fused gather-mean + relu + MFMA dual GEMM ----
    gather_gemm2_kernel<<<NT, 256, 0, stream>>>(
        t1, hs1, row_ptr, col_src, Ws2, Wn2, b2, hs2, t2, N);

    // ---- Layer 2 gather-mean -> h2 (bf16) ----
    {
        int waves = (N + 1) / 2;
        gather_mean64_kernel<<<(waves * 64 + 255) / 256, 256, 0, stream>>>(
            t2, hs2, row_ptr, col_src, h2, N);
    }

    // ---- Edge dots ----
    {
        int total = 2 * E * 8;
        edge_dot_kernel<<<(total + 255) / 256, 256, 0, stream>>>(
            h2, src, dst, nsrc, ndst, (float*)d_out, E);
    }
}

// Round 7
// 227.924 us; speedup vs baseline: 1.3002x; 1.3002x over previous
//
#include <hip/hip_runtime.h>

#define IN_DIM 128
#define HID_DIM 128
#define OUT_DIM 64

typedef short bf16x8 __attribute__((ext_vector_type(8)));   // 8 bf16 (4 VGPRs)
typedef float f32x4  __attribute__((ext_vector_type(4)));   // 4 fp32 acc

// ---- bf16 helpers (storage-only; math in fp32) ----
__device__ inline float bflo(unsigned int u) { return __uint_as_float(u << 16); }
__device__ inline float bfhi(unsigned int u) { return __uint_as_float(u & 0xffff0000u); }
__device__ inline unsigned short f2bf(float f) {
    unsigned int b = __float_as_uint(f);
    return (unsigned short)((b + 0x7FFFu + ((b >> 16) & 1u)) >> 16);  // RNE
}
__device__ inline unsigned int pack2(float a, float b) {
    return (unsigned int)f2bf(a) | ((unsigned int)f2bf(b) << 16);
}

// ===========================================================================
// CSR build step 1: histogram + per-edge rank (atomic return, ushort store).
// ===========================================================================
__global__ void hist_rank_kernel(const int* __restrict__ dst, int* __restrict__ cnt,
                                 unsigned short* __restrict__ rank, int E) {
    int e = blockIdx.x * blockDim.x + threadIdx.x;
    if (e < E) rank[e] = (unsigned short)atomicAdd(&cnt[dst[e]], 1);
}

__global__ void block_sums_kernel(const int* __restrict__ cnt, int* __restrict__ partial, int N) {
    __shared__ int s[256];
    int i = blockIdx.x * 256 + threadIdx.x;
    s[threadIdx.x] = (i < N) ? cnt[i] : 0;
    __syncthreads();
    for (int o = 128; o > 0; o >>= 1) {
        if (threadIdx.x < o) s[threadIdx.x] += s[threadIdx.x + o];
        __syncthreads();
    }
    if (threadIdx.x == 0) partial[blockIdx.x] = s[0];
}

__global__ void scan_partials_kernel(int* __restrict__ partial, int nB) {
    __shared__ int s[256];
    int v = (threadIdx.x < nB) ? partial[threadIdx.x] : 0;
    s[threadIdx.x] = v;
    __syncthreads();
    for (int o = 1; o < 256; o <<= 1) {
        int t = (threadIdx.x >= o) ? s[threadIdx.x - o] : 0;
        __syncthreads();
        s[threadIdx.x] += t;
        __syncthreads();
    }
    if (threadIdx.x < nB) partial[threadIdx.x] = s[threadIdx.x] - v;  // exclusive
}

__global__ void scan_chunks_kernel(const int* __restrict__ cnt, const int* __restrict__ partial,
                                   int* __restrict__ row_ptr, int N) {
    __shared__ int s[256];
    int i = blockIdx.x * 256 + threadIdx.x;
    int v = (i < N) ? cnt[i] : 0;
    s[threadIdx.x] = v;
    __syncthreads();
    for (int o = 1; o < 256; o <<= 1) {
        int t = (threadIdx.x >= o) ? s[threadIdx.x - o] : 0;
        __syncthreads();
        s[threadIdx.x] += t;
        __syncthreads();
    }
    int incl = s[threadIdx.x];
    int base = partial[blockIdx.x];
    if (i < N) row_ptr[i] = base + incl - v;
    if (i == N - 1) row_ptr[N] = base + incl;
}

// ===========================================================================
// Fused layer-1: blocks [0, FB) run the non-atomic CSR scatter (ushort);
// blocks [FB, FB+NGB) loop over MFMA dual-GEMM tiles (4 tiles/block).
// GEMM: hs[n] = x[n]@Wself + b (fp32) ; t[n] = x[n]@Wneigh (bf16).
// ===========================================================================
__global__ __launch_bounds__(256) void gemm1_fill_kernel(
        const float* __restrict__ x,
        const float* __restrict__ Wself,
        const float* __restrict__ Wneigh,
        const float* __restrict__ bias,
        float* __restrict__ hs,
        unsigned short* __restrict__ t,
        int N, int NT, int FB, int NGB,
        const int* __restrict__ src,
        const int* __restrict__ dst,
        const int* __restrict__ row_ptr,
        const unsigned short* __restrict__ rank,
        unsigned short* __restrict__ col_src,
        int E) {
    constexpr int DOUT = HID_DIM;
    constexpr int K   = 128;
    constexpr int MT  = 64;
    constexpr int WC  = 2 * DOUT;
    constexpr int SL  = WC / 4;      // 64
    constexpr int TN  = SL / 16;     // 4
    constexpr int TM  = MT / 16;     // 4
    constexpr int KS  = K / 32;      // 4
    constexpr int LDA = K + 8;

    __shared__ unsigned short sA[MT][LDA];

    const int tid = threadIdx.x;

    if ((int)blockIdx.x < FB) {
        int base = (int)blockIdx.x * 1024;
        #pragma unroll
        for (int k = 0; k < 4; ++k) {
            int e = base + k * 256 + tid;
            if (e < E) {
                int d = dst[e];
                col_src[row_ptr[d] + (int)rank[e]] = (unsigned short)src[e];
            }
        }
        return;
    }

    const int gb  = (int)blockIdx.x - FB;
    const int w   = tid >> 6;
    const int l   = tid & 63;
    const int l16 = l & 15;
    const int lhi = l >> 4;

    bf16x8 breg[TN][KS];
    float  bval[TN];
    #pragma unroll
    for (int tn = 0; tn < TN; ++tn) {
        const int c = w * SL + tn * 16 + l16;
        const bool self = (c < DOUT);
        const float* W = self ? &Wself[c] : &Wneigh[c - DOUT];
        bval[tn] = self ? bias[c] : 0.0f;
        #pragma unroll
        for (int ks = 0; ks < KS; ++ks) {
            const int k0 = ks * 32 + lhi * 8;
            bf16x8 f;
            #pragma unroll
            for (int j = 0; j < 8; ++j)
                f[j] = (short)f2bf(W[(size_t)(k0 + j) * DOUT]);
            breg[tn][ks] = f;
        }
    }

    for (int tile = gb; tile < NT; tile += NGB) {
        const int n0 = tile * MT;
        __syncthreads();
        #pragma unroll
        for (int it = 0; it < 8; ++it) {
            int flat = it * 256 + tid;
            int r  = flat >> 5;
            int c4 = flat & 31;
            float4 v = {0, 0, 0, 0};
            if (n0 + r < N) v = *(const float4*)&x[(size_t)(n0 + r) * K + c4 * 4];
            ushort4 p;
            p.x = f2bf(v.x); p.y = f2bf(v.y); p.z = f2bf(v.z); p.w = f2bf(v.w);
            *(ushort4*)&sA[r][c4 * 4] = p;
        }
        __syncthreads();

        f32x4 acc[TN][TM];
        #pragma unroll
        for (int tn = 0; tn < TN; ++tn)
            #pragma unroll
            for (int tm = 0; tm < TM; ++tm)
                acc[tn][tm] = (f32x4){0.0f, 0.0f, 0.0f, 0.0f};

        #pragma unroll
        for (int ks = 0; ks < KS; ++ks) {
            bf16x8 a[TM];
            #pragma unroll
            for (int tm = 0; tm < TM; ++tm)
                a[tm] = *(const bf16x8*)&sA[tm * 16 + l16][ks * 32 + lhi * 8];
            #pragma unroll
            for (int tn = 0; tn < TN; ++tn)
                #pragma unroll
                for (int tm = 0; tm < TM; ++tm)
                    acc[tn][tm] = __builtin_amdgcn_mfma_f32_16x16x32_bf16(
                        a[tm], breg[tn][ks], acc[tn][tm], 0, 0, 0);
        }

        #pragma unroll
        for (int tn = 0; tn < TN; ++tn) {
            const int c = w * SL + tn * 16 + l16;
            const bool self = (c < DOUT);
            const int cc = self ? c : c - DOUT;
            #pragma unroll
            for (int tm = 0; tm < TM; ++tm) {
                #pragma unroll
                for (int r = 0; r < 4; ++r) {
                    const int n = n0 + tm * 16 + lhi * 4 + r;
                    if (n < N) {
                        const float v = acc[tn][tm][r] + bval[tn];
                        if (self) hs[(size_t)n * DOUT + cc] = v;
                        else      t [(size_t)n * DOUT + cc] = f2bf(v);
                    }
                }
            }
        }
    }
}

// ===========================================================================
// Gather-mean layer 1 (D=128): one 64-lane wave per node (max MLP).
// out (bf16) = relu(base + mean t[neighbors])  — bf16 since gemm2 converts anyway.
// ===========================================================================
__global__ void gather_mean128_kernel(const unsigned short* __restrict__ t,
                                      const float* __restrict__ base,
                                      const int* __restrict__ row_ptr,
                                      const unsigned short* __restrict__ col_src,
                                      unsigned short* __restrict__ out, int N) {
    int node = (blockIdx.x * blockDim.x + threadIdx.x) >> 6;
    int lane = threadIdx.x & 63;
    if (node >= N) return;
    const int beg = row_ptr[node], end = row_ptr[node + 1];
    const float rdeg = 1.0f / fmaxf((float)(end - beg), 1.0f);
    const int off = lane * 2;

    float a0x = 0, a0y = 0, a1x = 0, a1y = 0, a2x = 0, a2y = 0, a3x = 0, a3y = 0;
    int i = beg;
    for (; i + 4 <= end; i += 4) {
        int s0 = col_src[i], s1 = col_src[i + 1], s2 = col_src[i + 2], s3 = col_src[i + 3];
        unsigned int u0 = *(const unsigned int*)&t[(size_t)s0 * 128 + off];
        unsigned int u1 = *(const unsigned int*)&t[(size_t)s1 * 128 + off];
        unsigned int u2 = *(const unsigned int*)&t[(size_t)s2 * 128 + off];
        unsigned int u3 = *(const unsigned int*)&t[(size_t)s3 * 128 + off];
        a0x += bflo(u0); a0y += bfhi(u0);
        a1x += bflo(u1); a1y += bfhi(u1);
        a2x += bflo(u2); a2y += bfhi(u2);
        a3x += bflo(u3); a3y += bfhi(u3);
    }
    for (; i < end; ++i) {
        unsigned int u = *(const unsigned int*)&t[(size_t)col_src[i] * 128 + off];
        a0x += bflo(u); a0y += bfhi(u);
    }
    float ax = (a0x + a1x) + (a2x + a3x);
    float ay = (a0y + a1y) + (a2y + a3y);
    float2 b = *(const float2*)&base[(size_t)node * 128 + off];
    float ox = fmaxf(b.x + ax * rdeg, 0.0f);
    float oy = fmaxf(b.y + ay * rdeg, 0.0f);
    *(unsigned int*)&out[(size_t)node * 128 + off] = pack2(ox, oy);
}

// ===========================================================================
// Layer-2 MFMA dual GEMM, bf16 input (h1): hs2 = h1@Ws2 + b2 ; t2 = h1@Wn2.
// A-tile staging is a pure bf16 copy (uint4 = 8 bf16 per thread-chunk).
// ===========================================================================
__global__ __launch_bounds__(256) void gemm2_kernel(
        const unsigned short* __restrict__ x,   // h1 bf16 [N][128]
        const float* __restrict__ Wself,
        const float* __restrict__ Wneigh,
        const float* __restrict__ bias,
        float* __restrict__ hs2,
        unsigned short* __restrict__ t2,
        int N) {
    constexpr int DOUT = OUT_DIM;
    constexpr int K   = 128;
    constexpr int MT  = 64;
    constexpr int WC  = 2 * DOUT;    // 128
    constexpr int SL  = WC / 4;      // 32
    constexpr int TN  = SL / 16;     // 2
    constexpr int TM  = MT / 16;     // 4
    constexpr int KS  = K / 32;      // 4
    constexpr int LDA = K + 8;

    __shared__ unsigned short sA[MT][LDA];

    const int tid = threadIdx.x;
    const int w   = tid >> 6;
    const int l   = tid & 63;
    const int l16 = l & 15;
    const int lhi = l >> 4;

    bf16x8 breg[TN][KS];
    float  bval[TN];
    #pragma unroll
    for (int tn = 0; tn < TN; ++tn) {
        const int c = w * SL + tn * 16 + l16;
        const bool self = (c < DOUT);
        const float* W = self ? &Wself[c] : &Wneigh[c - DOUT];
        bval[tn] = self ? bias[c] : 0.0f;
        #pragma unroll
        for (int ks = 0; ks < KS; ++ks) {
            const int k0 = ks * 32 + lhi * 8;
            bf16x8 f;
            #pragma unroll
            for (int j = 0; j < 8; ++j)
                f[j] = (short)f2bf(W[(size_t)(k0 + j) * DOUT]);
            breg[tn][ks] = f;
        }
    }

    const int n0 = (int)blockIdx.x * MT;
    // ---- stage A tile: 64 x 128 bf16 copy (uint4 = 8 shorts per chunk) ----
    #pragma unroll
    for (int it = 0; it < 4; ++it) {
        int flat = it * 256 + tid;       // 0..1023
        int r  = flat >> 4;              // 16 uint4 chunks per row
        int c8 = flat & 15;
        uint4 v = {0, 0, 0, 0};
        if (n0 + r < N) v = *(const uint4*)&x[(size_t)(n0 + r) * K + c8 * 8];
        *(uint4*)&sA[r][c8 * 8] = v;
    }
    __syncthreads();

    f32x4 acc[TN][TM];
    #pragma unroll
    for (int tn = 0; tn < TN; ++tn)
        #pragma unroll
        for (int tm = 0; tm < TM; ++tm)
            acc[tn][tm] = (f32x4){0.0f, 0.0f, 0.0f, 0.0f};

    #pragma unroll
    for (int ks = 0; ks < KS; ++ks) {
        bf16x8 a[TM];
        #pragma unroll
        for (int tm = 0; tm < TM; ++tm)
            a[tm] = *(const bf16x8*)&sA[tm * 16 + l16][ks * 32 + lhi * 8];
        #pragma unroll
        for (int tn = 0; tn < TN; ++tn)
            #pragma unroll
            for (int tm = 0; tm < TM; ++tm)
                acc[tn][tm] = __builtin_amdgcn_mfma_f32_16x16x32_bf16(
                    a[tm], breg[tn][ks], acc[tn][tm], 0, 0, 0);
    }

    #pragma unroll
    for (int tn = 0; tn < TN; ++tn) {
        const int c = w * SL + tn * 16 + l16;
        const bool self = (c < DOUT);
        const int cc = self ? c : c - DOUT;
        #pragma unroll
        for (int tm = 0; tm < TM; ++tm) {
            #pragma unroll
            for (int r = 0; r < 4; ++r) {
                const int n = n0 + tm * 16 + lhi * 4 + r;
                if (n < N) {
                    const float v = acc[tn][tm][r] + bval[tn];
                    if (self) hs2[(size_t)n * DOUT + cc] = v;
                    else      t2 [(size_t)n * DOUT + cc] = f2bf(v);
                }
            }
        }
    }
}

// ===========================================================================
// Gather-mean layer 2 (D=64): 32 lanes per node (2 nodes/wave), bf16 out.
// ===========================================================================
__global__ void gather_mean64_kernel(const unsigned short* __restrict__ t,
                                     const float* __restrict__ base,
                                     const int* __restrict__ row_ptr,
                                     const unsigned short* __restrict__ col_src,
                                     unsigned short* __restrict__ out, int N) {
    int tid  = blockIdx.x * blockDim.x + threadIdx.x;
    int node = (tid >> 6) * 2 + ((tid >> 5) & 1);
    int m    = tid & 31;
    if (node >= N) return;
    const int beg = row_ptr[node], end = row_ptr[node + 1];
    const float rdeg = 1.0f / fmaxf((float)(end - beg), 1.0f);
    const int off = m * 2;

    float a0x = 0, a0y = 0, a1x = 0, a1y = 0, a2x = 0, a2y = 0, a3x = 0, a3y = 0;
    int i = beg;
    for (; i + 4 <= end; i += 4) {
        int s0 = col_src[i], s1 = col_src[i + 1], s2 = col_src[i + 2], s3 = col_src[i + 3];
        unsigned int u0 = *(const unsigned int*)&t[(size_t)s0 * 64 + off];
        unsigned int u1 = *(const unsigned int*)&t[(size_t)s1 * 64 + off];
        unsigned int u2 = *(const unsigned int*)&t[(size_t)s2 * 64 + off];
        unsigned int u3 = *(const unsigned int*)&t[(size_t)s3 * 64 + off];
        a0x += bflo(u0); a0y += bfhi(u0);
        a1x += bflo(u1); a1y += bfhi(u1);
        a2x += bflo(u2); a2y += bfhi(u2);
        a3x += bflo(u3); a3y += bfhi(u3);
    }
    for (; i < end; ++i) {
        unsigned int u = *(const unsigned int*)&t[(size_t)col_src[i] * 64 + off];
        a0x += bflo(u); a0y += bfhi(u);
    }
    float ax = (a0x + a1x) + (a2x + a3x);
    float ay = (a0y + a1y) + (a2y + a3y);
    float2 b = *(const float2*)&base[(size_t)node * 64 + off];
    *(unsigned int*)&out[(size_t)node * 64 + off] = pack2(b.x + ax * rdeg, b.y + ay * rdeg);
}

// ===========================================================================
// Edge dot on bf16 h (D=64, 128B rows): 8 lanes/edge, uint4 (8 bf16) loads.
// ===========================================================================
__global__ void edge_dot_kernel(const unsigned short* __restrict__ h,
                                const int* __restrict__ src,
                                const int* __restrict__ dst,
                                const int* __restrict__ nsrc,
                                const int* __restrict__ ndst,
                                float* __restrict__ out,
                                int E) {
    int tid = blockIdx.x * blockDim.x + threadIdx.x;
    int eg = tid >> 3;
    int l  = tid & 7;
    if (eg >= 2 * E) return;
    int s, t;
    if (eg < E) { s = src[eg];      t = dst[eg]; }
    else        { s = nsrc[eg - E]; t = ndst[eg - E]; }
    const uint4 a = *reinterpret_cast<const uint4*>(&h[(size_t)s * OUT_DIM + l * 8]);
    const uint4 b = *reinterpret_cast<const uint4*>(&h[(size_t)t * OUT_DIM + l * 8]);
    float v = bflo(a.x) * bflo(b.x) + bfhi(a.x) * bfhi(b.x)
            + bflo(a.y) * bflo(b.y) + bfhi(a.y) * bfhi(b.y)
            + bflo(a.z) * bflo(b.z) + bfhi(a.z) * bfhi(b.z)
            + bflo(a.w) * bflo(b.w) + bfhi(a.w) * bfhi(b.w);
    v += __shfl_xor(v, 4, 8);
    v += __shfl_xor(v, 2, 8);
    v += __shfl_xor(v, 1, 8);
    if (l == 0) out[eg] = v;
}

extern "C" void kernel_launch(void* const* d_in, const int* in_sizes, int n_in,
                              void* d_out, int out_size, void* d_ws, size_t ws_size,
                              hipStream_t stream) {
    const float* feat = (const float*)d_in[0];
    const float* Ws1  = (const float*)d_in[1];
    const float* Wn1  = (const float*)d_in[2];
    const float* b1   = (const float*)d_in[3];
    const float* Ws2  = (const float*)d_in[4];
    const float* Wn2  = (const float*)d_in[5];
    const float* b2   = (const float*)d_in[6];
    const int* src  = (const int*)d_in[7];
    const int* dst  = (const int*)d_in[8];
    const int* nsrc = (const int*)d_in[9];
    const int* ndst = (const int*)d_in[10];
    const int E = in_sizes[7];
    const int N = in_sizes[0] / IN_DIM;
    const int NB = (N + 255) / 256;
    const int NT = (N + 63) / 64;           // MFMA node tiles
    const int FB = (E + 1023) / 1024;       // scatter blocks
    const int NGB = (NT + 3) / 4;           // gemm blocks (4 tiles each)

    // ---- workspace layout ----
    int* wsi     = (int*)d_ws;
    int* cnt     = wsi;                  // N
    int* row_ptr = cnt + N;              // N+1
    int* partial = row_ptr + N + 1;      // 256
    unsigned short* rank    = (unsigned short*)(partial + 256);  // E
    unsigned short* col_src = rank + E;                          // E
    size_t int_count = (size_t)(2 * N + 1 + 256) + (size_t)E;    // 2*E ushorts = E ints
    int_count = (int_count + 3) & ~(size_t)3;
    unsigned short* t1 = (unsigned short*)(wsi + int_count);         // N*128 bf16
    float* hs1 = (float*)(t1 + (size_t)N * HID_DIM);                 // N*128 fp32
    unsigned short* h1 = (unsigned short*)(hs1 + (size_t)N * HID_DIM);  // N*128 bf16
    unsigned short* t2 = h1 + (size_t)N * HID_DIM;                   // N*64 bf16
    float* hs2 = (float*)(t2 + (size_t)N * OUT_DIM);                 // N*64 fp32
    unsigned short* h2 = (unsigned short*)(hs2 + (size_t)N * OUT_DIM);  // N*64 bf16

    // ---- CSR build: hist(+rank) -> scan ----
    hipMemsetAsync(cnt, 0, sizeof(int) * (size_t)N, stream);
    hist_rank_kernel<<<(E + 255) / 256, 256, 0, stream>>>(dst, cnt, rank, E);
    block_sums_kernel<<<NB, 256, 0, stream>>>(cnt, partial, N);
    scan_partials_kernel<<<1, 256, 0, stream>>>(partial, NB);
    scan_chunks_kernel<<<NB, 256, 0, stream>>>(cnt, partial, row_ptr, N);

    // ---- Layer 1 GEMM (multi-tile) fused with non-atomic CSR scatter ----
    gemm1_fill_kernel<<<FB + NGB, 256, 0, stream>>>(
        feat, Ws1, Wn1, b1, hs1, t1, N, NT, FB, NGB,
        src, dst, row_ptr, rank, col_src, E);

    // ---- Layer 1 gather-mean + relu -> h1 (bf16; one wave per node) ----
    gather_mean128_kernel<<<(N * 64 + 255) / 256, 256, 0, stream>>>(
        t1, hs1, row_ptr, col_src, h1, N);

    // ---- Layer 2 GEMM (bf16 input) ----
    gemm2_kernel<<<NT, 256, 0, stream>>>(
        h1, Ws2, Wn2, b2, hs2, t2, N);

    // ---- Layer 2 gather-mean -> h2 (bf16) ----
    {
        int waves = (N + 1) / 2;
        gather_mean64_kernel<<<(waves * 64 + 255) / 256, 256, 0, stream>>>(
            t2, hs2, row_ptr, col_src, h2, N);
    }

    // ---- Edge dots ----
    {
        int total = 2 * E * 8;
        edge_dot_kernel<<<(total + 255) / 256, 256, 0, stream>>>(
            h2, src, dst, nsrc, ndst, (float*)d_out, E);
    }
}

// Round 8
// 197.908 us; speedup vs baseline: 1.4974x; 1.1517x over previous
//
#include <hip/hip_runtime.h>

#define IN_DIM 128
#define HID_DIM 128
#define OUT_DIM 64

typedef short bf16x8 __attribute__((ext_vector_type(8)));   // 8 bf16 (4 VGPRs)
typedef float f32x4  __attribute__((ext_vector_type(4)));   // 4 fp32 acc

// ---- bf16 helpers (storage-only; math in fp32) ----
__device__ inline float bflo(unsigned int u) { return __uint_as_float(u << 16); }
__device__ inline float bfhi(unsigned int u) { return __uint_as_float(u & 0xffff0000u); }
__device__ inline unsigned short f2bf(float f) {
    unsigned int b = __float_as_uint(f);
    return (unsigned short)((b + 0x7FFFu + ((b >> 16) & 1u)) >> 16);  // RNE
}
__device__ inline unsigned int pack2(float a, float b) {
    return (unsigned int)f2bf(a) | ((unsigned int)f2bf(b) << 16);
}

// ===========================================================================
// Weight transpose+convert (once): Wt1[c][k]=W1[k][c] bf16 (c<128: Wself1,
// else Wneigh1); Wt2[c][k] same for layer 2 (c<64: Wself2, else Wneigh2).
// Makes the per-wave MFMA B-fragment a single 16B contiguous load.
// ===========================================================================
__global__ void wtrans_kernel(const float* __restrict__ Ws1, const float* __restrict__ Wn1,
                              const float* __restrict__ Ws2, const float* __restrict__ Wn2,
                              unsigned short* __restrict__ Wt1, unsigned short* __restrict__ Wt2) {
    int tid = blockIdx.x * blockDim.x + threadIdx.x;
    if (tid < 4096) {               // Wt1: 256 cols x 16 chunks of 8
        int c = tid >> 4, k0 = (tid & 15) << 3;
        const float* W = (c < 128) ? (Ws1 + c) : (Wn1 + (c - 128));
        ushort4 a, b;
        a.x = f2bf(W[(size_t)(k0 + 0) * 128]); a.y = f2bf(W[(size_t)(k0 + 1) * 128]);
        a.z = f2bf(W[(size_t)(k0 + 2) * 128]); a.w = f2bf(W[(size_t)(k0 + 3) * 128]);
        b.x = f2bf(W[(size_t)(k0 + 4) * 128]); b.y = f2bf(W[(size_t)(k0 + 5) * 128]);
        b.z = f2bf(W[(size_t)(k0 + 6) * 128]); b.w = f2bf(W[(size_t)(k0 + 7) * 128]);
        *(ushort4*)&Wt1[c * 128 + k0]     = a;
        *(ushort4*)&Wt1[c * 128 + k0 + 4] = b;
    } else if (tid < 6144) {        // Wt2: 128 cols x 16 chunks of 8
        int t = tid - 4096;
        int c = t >> 4, k0 = (t & 15) << 3;
        const float* W = (c < 64) ? (Ws2 + c) : (Wn2 + (c - 64));
        ushort4 a, b;
        a.x = f2bf(W[(size_t)(k0 + 0) * 64]); a.y = f2bf(W[(size_t)(k0 + 1) * 64]);
        a.z = f2bf(W[(size_t)(k0 + 2) * 64]); a.w = f2bf(W[(size_t)(k0 + 3) * 64]);
        b.x = f2bf(W[(size_t)(k0 + 4) * 64]); b.y = f2bf(W[(size_t)(k0 + 5) * 64]);
        b.z = f2bf(W[(size_t)(k0 + 6) * 64]); b.w = f2bf(W[(size_t)(k0 + 7) * 64]);
        *(ushort4*)&Wt2[c * 128 + k0]     = a;
        *(ushort4*)&Wt2[c * 128 + k0 + 4] = b;
    }
}

// ===========================================================================
// CSR build: histogram + per-edge rank -> 3-kernel scan.
// ===========================================================================
__global__ void hist_rank_kernel(const int* __restrict__ dst, int* __restrict__ cnt,
                                 unsigned short* __restrict__ rank, int E) {
    int e = blockIdx.x * blockDim.x + threadIdx.x;
    if (e < E) rank[e] = (unsigned short)atomicAdd(&cnt[dst[e]], 1);
}

__global__ void block_sums_kernel(const int* __restrict__ cnt, int* __restrict__ partial, int N) {
    __shared__ int s[256];
    int i = blockIdx.x * 256 + threadIdx.x;
    s[threadIdx.x] = (i < N) ? cnt[i] : 0;
    __syncthreads();
    for (int o = 128; o > 0; o >>= 1) {
        if (threadIdx.x < o) s[threadIdx.x] += s[threadIdx.x + o];
        __syncthreads();
    }
    if (threadIdx.x == 0) partial[blockIdx.x] = s[0];
}

__global__ void scan_partials_kernel(int* __restrict__ partial, int nB) {
    __shared__ int s[256];
    int v = (threadIdx.x < nB) ? partial[threadIdx.x] : 0;
    s[threadIdx.x] = v;
    __syncthreads();
    for (int o = 1; o < 256; o <<= 1) {
        int t = (threadIdx.x >= o) ? s[threadIdx.x - o] : 0;
        __syncthreads();
        s[threadIdx.x] += t;
        __syncthreads();
    }
    if (threadIdx.x < nB) partial[threadIdx.x] = s[threadIdx.x] - v;  // exclusive
}

__global__ void scan_chunks_kernel(const int* __restrict__ cnt, const int* __restrict__ partial,
                                   int* __restrict__ row_ptr, int N) {
    __shared__ int s[256];
    int i = blockIdx.x * 256 + threadIdx.x;
    int v = (i < N) ? cnt[i] : 0;
    s[threadIdx.x] = v;
    __syncthreads();
    for (int o = 1; o < 256; o <<= 1) {
        int t = (threadIdx.x >= o) ? s[threadIdx.x - o] : 0;
        __syncthreads();
        s[threadIdx.x] += t;
        __syncthreads();
    }
    int incl = s[threadIdx.x];
    int base = partial[blockIdx.x];
    if (i < N) row_ptr[i] = base + incl - v;
    if (i == N - 1) row_ptr[N] = base + incl;
}

// ===========================================================================
// Fused layer-1: blocks [0, FB) = non-atomic CSR scatter; blocks [FB, FB+NT)
// = one 64-node MFMA dual-GEMM tile each (weights from pre-transposed Wt1).
// GEMM: hs[n] = x[n]@Ws1 + b1 (fp32) ; t[n] = x[n]@Wn1 (bf16).
// ===========================================================================
__global__ __launch_bounds__(256) void gemm1_fill_kernel(
        const float* __restrict__ x,
        const unsigned short* __restrict__ Wt,   // [256][128] bf16
        const float* __restrict__ bias,
        float* __restrict__ hs,
        unsigned short* __restrict__ t,
        int N, int FB,
        const int* __restrict__ src,
        const int* __restrict__ dst,
        const int* __restrict__ row_ptr,
        const unsigned short* __restrict__ rank,
        unsigned short* __restrict__ col_src,
        int E) {
    constexpr int DOUT = HID_DIM;
    constexpr int K   = 128;
    constexpr int MT  = 64;
    constexpr int SL  = 2 * DOUT / 4;   // 64 cols per wave
    constexpr int TN  = SL / 16;        // 4
    constexpr int TM  = MT / 16;        // 4
    constexpr int KS  = K / 32;         // 4
    constexpr int LDA = K + 8;

    __shared__ unsigned short sA[MT][LDA];

    const int tid = threadIdx.x;

    if ((int)blockIdx.x < FB) {
        int base = (int)blockIdx.x * 1024;
        #pragma unroll
        for (int k = 0; k < 4; ++k) {
            int e = base + k * 256 + tid;
            if (e < E) {
                int d = dst[e];
                col_src[row_ptr[d] + (int)rank[e]] = (unsigned short)src[e];
            }
        }
        return;
    }

    const int w   = tid >> 6;
    const int l   = tid & 63;
    const int l16 = l & 15;
    const int lhi = l >> 4;
    const int n0  = ((int)blockIdx.x - FB) * MT;

    // ---- stage A tile: 64 x 128 fp32 -> bf16 in LDS ----
    #pragma unroll
    for (int it = 0; it < 8; ++it) {
        int flat = it * 256 + tid;
        int r  = flat >> 5;
        int c4 = flat & 31;
        float4 v = {0, 0, 0, 0};
        if (n0 + r < N) v = *(const float4*)&x[(size_t)(n0 + r) * K + c4 * 4];
        ushort4 p;
        p.x = f2bf(v.x); p.y = f2bf(v.y); p.z = f2bf(v.z); p.w = f2bf(v.w);
        *(ushort4*)&sA[r][c4 * 4] = p;
    }

    // ---- weight fragments: one 16B load each from Wt ----
    bf16x8 breg[TN][KS];
    float  bval[TN];
    #pragma unroll
    for (int tn = 0; tn < TN; ++tn) {
        const int c = w * SL + tn * 16 + l16;
        bval[tn] = (c < DOUT) ? bias[c] : 0.0f;
        #pragma unroll
        for (int ks = 0; ks < KS; ++ks)
            breg[tn][ks] = *(const bf16x8*)&Wt[c * 128 + ks * 32 + lhi * 8];
    }
    __syncthreads();

    f32x4 acc[TN][TM];
    #pragma unroll
    for (int tn = 0; tn < TN; ++tn)
        #pragma unroll
        for (int tm = 0; tm < TM; ++tm)
            acc[tn][tm] = (f32x4){0.0f, 0.0f, 0.0f, 0.0f};

    #pragma unroll
    for (int ks = 0; ks < KS; ++ks) {
        bf16x8 a[TM];
        #pragma unroll
        for (int tm = 0; tm < TM; ++tm)
            a[tm] = *(const bf16x8*)&sA[tm * 16 + l16][ks * 32 + lhi * 8];
        #pragma unroll
        for (int tn = 0; tn < TN; ++tn)
            #pragma unroll
            for (int tm = 0; tm < TM; ++tm)
                acc[tn][tm] = __builtin_amdgcn_mfma_f32_16x16x32_bf16(
                    a[tm], breg[tn][ks], acc[tn][tm], 0, 0, 0);
    }

    // ---- epilogue: C/D layout col=lane&15, row=(lane>>4)*4+r ----
    #pragma unroll
    for (int tn = 0; tn < TN; ++tn) {
        const int c = w * SL + tn * 16 + l16;
        const bool self = (c < DOUT);
        const int cc = self ? c : c - DOUT;
        #pragma unroll
        for (int tm = 0; tm < TM; ++tm) {
            #pragma unroll
            for (int r = 0; r < 4; ++r) {
                const int n = n0 + tm * 16 + lhi * 4 + r;
                if (n < N) {
                    const float v = acc[tn][tm][r] + bval[tn];
                    if (self) hs[(size_t)n * DOUT + cc] = v;
                    else      t [(size_t)n * DOUT + cc] = f2bf(v);
                }
            }
        }
    }
}

// ===========================================================================
// Gather-mean layer 1 (D=128): one 64-lane wave per node (max MLP).
// out (bf16) = relu(base + mean t[neighbors])
// ===========================================================================
__global__ void gather_mean128_kernel(const unsigned short* __restrict__ t,
                                      const float* __restrict__ base,
                                      const int* __restrict__ row_ptr,
                                      const unsigned short* __restrict__ col_src,
                                      unsigned short* __restrict__ out, int N) {
    int node = (blockIdx.x * blockDim.x + threadIdx.x) >> 6;
    int lane = threadIdx.x & 63;
    if (node >= N) return;
    const int beg = row_ptr[node], end = row_ptr[node + 1];
    const float rdeg = 1.0f / fmaxf((float)(end - beg), 1.0f);
    const int off = lane * 2;

    float a0x = 0, a0y = 0, a1x = 0, a1y = 0, a2x = 0, a2y = 0, a3x = 0, a3y = 0;
    int i = beg;
    for (; i + 4 <= end; i += 4) {
        int s0 = col_src[i], s1 = col_src[i + 1], s2 = col_src[i + 2], s3 = col_src[i + 3];
        unsigned int u0 = *(const unsigned int*)&t[(size_t)s0 * 128 + off];
        unsigned int u1 = *(const unsigned int*)&t[(size_t)s1 * 128 + off];
        unsigned int u2 = *(const unsigned int*)&t[(size_t)s2 * 128 + off];
        unsigned int u3 = *(const unsigned int*)&t[(size_t)s3 * 128 + off];
        a0x += bflo(u0); a0y += bfhi(u0);
        a1x += bflo(u1); a1y += bfhi(u1);
        a2x += bflo(u2); a2y += bfhi(u2);
        a3x += bflo(u3); a3y += bfhi(u3);
    }
    for (; i < end; ++i) {
        unsigned int u = *(const unsigned int*)&t[(size_t)col_src[i] * 128 + off];
        a0x += bflo(u); a0y += bfhi(u);
    }
    float ax = (a0x + a1x) + (a2x + a3x);
    float ay = (a0y + a1y) + (a2y + a3y);
    float2 b = *(const float2*)&base[(size_t)node * 128 + off];
    float ox = fmaxf(b.x + ax * rdeg, 0.0f);
    float oy = fmaxf(b.y + ay * rdeg, 0.0f);
    *(unsigned int*)&out[(size_t)node * 128 + off] = pack2(ox, oy);
}

// ===========================================================================
// Layer-2 MFMA dual GEMM, bf16 input (h1), weights from Wt2.
// ===========================================================================
__global__ __launch_bounds__(256) void gemm2_kernel(
        const unsigned short* __restrict__ x,   // h1 bf16 [N][128]
        const unsigned short* __restrict__ Wt,  // [128][128] bf16
        const float* __restrict__ bias,
        float* __restrict__ hs2,
        unsigned short* __restrict__ t2,
        int N) {
    constexpr int DOUT = OUT_DIM;
    constexpr int K   = 128;
    constexpr int MT  = 64;
    constexpr int SL  = 2 * DOUT / 4;   // 32
    constexpr int TN  = SL / 16;        // 2
    constexpr int TM  = MT / 16;        // 4
    constexpr int KS  = K / 32;         // 4
    constexpr int LDA = K + 8;

    __shared__ unsigned short sA[MT][LDA];

    const int tid = threadIdx.x;
    const int w   = tid >> 6;
    const int l   = tid & 63;
    const int l16 = l & 15;
    const int lhi = l >> 4;
    const int n0  = (int)blockIdx.x * MT;

    // ---- stage A tile: 64 x 128 bf16 copy ----
    #pragma unroll
    for (int it = 0; it < 4; ++it) {
        int flat = it * 256 + tid;
        int r  = flat >> 4;
        int c8 = flat & 15;
        uint4 v = {0, 0, 0, 0};
        if (n0 + r < N) v = *(const uint4*)&x[(size_t)(n0 + r) * K + c8 * 8];
        *(uint4*)&sA[r][c8 * 8] = v;
    }

    bf16x8 breg[TN][KS];
    float  bval[TN];
    #pragma unroll
    for (int tn = 0; tn < TN; ++tn) {
        const int c = w * SL + tn * 16 + l16;
        bval[tn] = (c < DOUT) ? bias[c] : 0.0f;
        #pragma unroll
        for (int ks = 0; ks < KS; ++ks)
            breg[tn][ks] = *(const bf16x8*)&Wt[c * 128 + ks * 32 + lhi * 8];
    }
    __syncthreads();

    f32x4 acc[TN][TM];
    #pragma unroll
    for (int tn = 0; tn < TN; ++tn)
        #pragma unroll
        for (int tm = 0; tm < TM; ++tm)
            acc[tn][tm] = (f32x4){0.0f, 0.0f, 0.0f, 0.0f};

    #pragma unroll
    for (int ks = 0; ks < KS; ++ks) {
        bf16x8 a[TM];
        #pragma unroll
        for (int tm = 0; tm < TM; ++tm)
            a[tm] = *(const bf16x8*)&sA[tm * 16 + l16][ks * 32 + lhi * 8];
        #pragma unroll
        for (int tn = 0; tn < TN; ++tn)
            #pragma unroll
            for (int tm = 0; tm < TM; ++tm)
                acc[tn][tm] = __builtin_amdgcn_mfma_f32_16x16x32_bf16(
                    a[tm], breg[tn][ks], acc[tn][tm], 0, 0, 0);
    }

    #pragma unroll
    for (int tn = 0; tn < TN; ++tn) {
        const int c = w * SL + tn * 16 + l16;
        const bool self = (c < DOUT);
        const int cc = self ? c : c - DOUT;
        #pragma unroll
        for (int tm = 0; tm < TM; ++tm) {
            #pragma unroll
            for (int r = 0; r < 4; ++r) {
                const int n = n0 + tm * 16 + lhi * 4 + r;
                if (n < N) {
                    const float v = acc[tn][tm][r] + bval[tn];
                    if (self) hs2[(size_t)n * DOUT + cc] = v;
                    else      t2 [(size_t)n * DOUT + cc] = f2bf(v);
                }
            }
        }
    }
}

// ===========================================================================
// Gather-mean layer 2 (D=64): 32 lanes per node (2 nodes/wave), bf16 out.
// ===========================================================================
__global__ void gather_mean64_kernel(const unsigned short* __restrict__ t,
                                     const float* __restrict__ base,
                                     const int* __restrict__ row_ptr,
                                     const unsigned short* __restrict__ col_src,
                                     unsigned short* __restrict__ out, int N) {
    int tid  = blockIdx.x * blockDim.x + threadIdx.x;
    int node = (tid >> 6) * 2 + ((tid >> 5) & 1);
    int m    = tid & 31;
    if (node >= N) return;
    const int beg = row_ptr[node], end = row_ptr[node + 1];
    const float rdeg = 1.0f / fmaxf((float)(end - beg), 1.0f);
    const int off = m * 2;

    float a0x = 0, a0y = 0, a1x = 0, a1y = 0, a2x = 0, a2y = 0, a3x = 0, a3y = 0;
    int i = beg;
    for (; i + 4 <= end; i += 4) {
        int s0 = col_src[i], s1 = col_src[i + 1], s2 = col_src[i + 2], s3 = col_src[i + 3];
        unsigned int u0 = *(const unsigned int*)&t[(size_t)s0 * 64 + off];
        unsigned int u1 = *(const unsigned int*)&t[(size_t)s1 * 64 + off];
        unsigned int u2 = *(const unsigned int*)&t[(size_t)s2 * 64 + off];
        unsigned int u3 = *(const unsigned int*)&t[(size_t)s3 * 64 + off];
        a0x += bflo(u0); a0y += bfhi(u0);
        a1x += bflo(u1); a1y += bfhi(u1);
        a2x += bflo(u2); a2y += bfhi(u2);
        a3x += bflo(u3); a3y += bfhi(u3);
    }
    for (; i < end; ++i) {
        unsigned int u = *(const unsigned int*)&t[(size_t)col_src[i] * 64 + off];
        a0x += bflo(u); a0y += bfhi(u);
    }
    float ax = (a0x + a1x) + (a2x + a3x);
    float ay = (a0y + a1y) + (a2y + a3y);
    float2 b = *(const float2*)&base[(size_t)node * 64 + off];
    *(unsigned int*)&out[(size_t)node * 64 + off] = pack2(b.x + ax * rdeg, b.y + ay * rdeg);
}

// ===========================================================================
// Edge dot on bf16 h (D=64, 128B rows): 8 lanes/edge, uint4 (8 bf16) loads.
// ===========================================================================
__global__ void edge_dot_kernel(const unsigned short* __restrict__ h,
                                const int* __restrict__ src,
                                const int* __restrict__ dst,
                                const int* __restrict__ nsrc,
                                const int* __restrict__ ndst,
                                float* __restrict__ out,
                                int E) {
    int tid = blockIdx.x * blockDim.x + threadIdx.x;
    int eg = tid >> 3;
    int l  = tid & 7;
    if (eg >= 2 * E) return;
    int s, t;
    if (eg < E) { s = src[eg];      t = dst[eg]; }
    else        { s = nsrc[eg - E]; t = ndst[eg - E]; }
    const uint4 a = *reinterpret_cast<const uint4*>(&h[(size_t)s * OUT_DIM + l * 8]);
    const uint4 b = *reinterpret_cast<const uint4*>(&h[(size_t)t * OUT_DIM + l * 8]);
    float v = bflo(a.x) * bflo(b.x) + bfhi(a.x) * bfhi(b.x)
            + bflo(a.y) * bflo(b.y) + bfhi(a.y) * bfhi(b.y)
            + bflo(a.z) * bflo(b.z) + bfhi(a.z) * bfhi(b.z)
            + bflo(a.w) * bflo(b.w) + bfhi(a.w) * bfhi(b.w);
    v += __shfl_xor(v, 4, 8);
    v += __shfl_xor(v, 2, 8);
    v += __shfl_xor(v, 1, 8);
    if (l == 0) out[eg] = v;
}

extern "C" void kernel_launch(void* const* d_in, const int* in_sizes, int n_in,
                              void* d_out, int out_size, void* d_ws, size_t ws_size,
                              hipStream_t stream) {
    const float* feat = (const float*)d_in[0];
    const float* Ws1  = (const float*)d_in[1];
    const float* Wn1  = (const float*)d_in[2];
    const float* b1   = (const float*)d_in[3];
    const float* Ws2  = (const float*)d_in[4];
    const float* Wn2  = (const float*)d_in[5];
    const float* b2   = (const float*)d_in[6];
    const int* src  = (const int*)d_in[7];
    const int* dst  = (const int*)d_in[8];
    const int* nsrc = (const int*)d_in[9];
    const int* ndst = (const int*)d_in[10];
    const int E = in_sizes[7];
    const int N = in_sizes[0] / IN_DIM;
    const int NB = (N + 255) / 256;
    const int NT = (N + 63) / 64;           // MFMA node tiles
    const int FB = (E + 1023) / 1024;       // scatter blocks

    // ---- workspace layout (16B-aligned big arrays first) ----
    char* wsb = (char*)d_ws;
    unsigned short* Wt1 = (unsigned short*)wsb;                         // [256][128] = 64KB
    unsigned short* Wt2 = Wt1 + 256 * 128;                              // [128][128] = 32KB
    unsigned short* t1  = Wt2 + 128 * 128;                              // N*128 bf16
    float* hs1          = (float*)(t1 + (size_t)N * HID_DIM);           // N*128 fp32
    unsigned short* h1  = (unsigned short*)(hs1 + (size_t)N * HID_DIM); // N*128 bf16
    unsigned short* t2  = h1 + (size_t)N * HID_DIM;                     // N*64 bf16
    float* hs2          = (float*)(t2 + (size_t)N * OUT_DIM);           // N*64 fp32
    unsigned short* h2  = (unsigned short*)(hs2 + (size_t)N * OUT_DIM); // N*64 bf16
    int* cnt            = (int*)(h2 + (size_t)N * OUT_DIM);             // N
    int* row_ptr        = cnt + N;                                      // N+1
    int* partial        = row_ptr + N + 1;                              // 256
    unsigned short* rank    = (unsigned short*)(partial + 256);         // E
    unsigned short* col_src = rank + E;                                 // E

    // ---- weight transpose (independent; done once per launch) ----
    wtrans_kernel<<<24, 256, 0, stream>>>(Ws1, Wn1, Ws2, Wn2, Wt1, Wt2);

    // ---- CSR build: hist(+rank) -> scan ----
    hipMemsetAsync(cnt, 0, sizeof(int) * (size_t)N, stream);
    hist_rank_kernel<<<(E + 255) / 256, 256, 0, stream>>>(dst, cnt, rank, E);
    block_sums_kernel<<<NB, 256, 0, stream>>>(cnt, partial, N);
    scan_partials_kernel<<<1, 256, 0, stream>>>(partial, NB);
    scan_chunks_kernel<<<NB, 256, 0, stream>>>(cnt, partial, row_ptr, N);

    // ---- Layer 1 GEMM (1 tile/block) fused with non-atomic CSR scatter ----
    gemm1_fill_kernel<<<FB + NT, 256, 0, stream>>>(
        feat, Wt1, b1, hs1, t1, N, FB,
        src, dst, row_ptr, rank, col_src, E);

    // ---- Layer 1 gather-mean + relu -> h1 (bf16; one wave per node) ----
    gather_mean128_kernel<<<(N * 64 + 255) / 256, 256, 0, stream>>>(
        t1, hs1, row_ptr, col_src, h1, N);

    // ---- Layer 2 GEMM (bf16 input) ----
    gemm2_kernel<<<NT, 256, 0, stream>>>(
        h1, Wt2, b2, hs2, t2, N);

    // ---- Layer 2 gather-mean -> h2 (bf16) ----
    {
        int waves = (N + 1) / 2;
        gather_mean64_kernel<<<(waves * 64 + 255) / 256, 256, 0, stream>>>(
            t2, hs2, row_ptr, col_src, h2, N);
    }

    // ---- Edge dots ----
    {
        int total = 2 * E * 8;
        edge_dot_kernel<<<(total + 255) / 256, 256, 0, stream>>>(
            h2, src, dst, nsrc, ndst, (float*)d_out, E);
    }
}

// Round 9
// 183.600 us; speedup vs baseline: 1.6141x; 1.0779x over previous
//
#include <hip/hip_runtime.h>

#define IN_DIM 128
#define HID_DIM 128
#define OUT_DIM 64

typedef short bf16x8 __attribute__((ext_vector_type(8)));   // 8 bf16 (4 VGPRs)
typedef float f32x4  __attribute__((ext_vector_type(4)));   // 4 fp32 acc

// ---- bf16 helpers (storage-only; math in fp32) ----
__device__ inline float bflo(unsigned int u) { return __uint_as_float(u << 16); }
__device__ inline float bfhi(unsigned int u) { return __uint_as_float(u & 0xffff0000u); }
__device__ inline unsigned short f2bf(float f) {
    unsigned int b = __float_as_uint(f);
    return (unsigned short)((b + 0x7FFFu + ((b >> 16) & 1u)) >> 16);  // RNE
}
__device__ inline unsigned int pack2(float a, float b) {
    return (unsigned int)f2bf(a) | ((unsigned int)f2bf(b) << 16);
}
__device__ inline float dot8(uint4 a, uint4 b) {
    return bflo(a.x) * bflo(b.x) + bfhi(a.x) * bfhi(b.x)
         + bflo(a.y) * bflo(b.y) + bfhi(a.y) * bfhi(b.y)
         + bflo(a.z) * bflo(b.z) + bfhi(a.z) * bfhi(b.z)
         + bflo(a.w) * bflo(b.w) + bfhi(a.w) * bfhi(b.w);
}

// ===========================================================================
// Fused: blocks [0,24) transpose+convert weights (Wt1 [256][128], Wt2 [128][128]
// bf16); blocks [24, ...) do histogram + per-edge rank (atomic return).
// ===========================================================================
__global__ void wtrans_hist_kernel(const float* __restrict__ Ws1, const float* __restrict__ Wn1,
                                   const float* __restrict__ Ws2, const float* __restrict__ Wn2,
                                   unsigned short* __restrict__ Wt1, unsigned short* __restrict__ Wt2,
                                   const int* __restrict__ dst, int* __restrict__ cnt,
                                   unsigned short* __restrict__ rank, int E) {
    if ((int)blockIdx.x < 24) {
        int tid = (int)blockIdx.x * 256 + threadIdx.x;
        if (tid < 4096) {               // Wt1: 256 cols x 16 chunks of 8
            int c = tid >> 4, k0 = (tid & 15) << 3;
            const float* W = (c < 128) ? (Ws1 + c) : (Wn1 + (c - 128));
            ushort4 a, b;
            a.x = f2bf(W[(size_t)(k0 + 0) * 128]); a.y = f2bf(W[(size_t)(k0 + 1) * 128]);
            a.z = f2bf(W[(size_t)(k0 + 2) * 128]); a.w = f2bf(W[(size_t)(k0 + 3) * 128]);
            b.x = f2bf(W[(size_t)(k0 + 4) * 128]); b.y = f2bf(W[(size_t)(k0 + 5) * 128]);
            b.z = f2bf(W[(size_t)(k0 + 6) * 128]); b.w = f2bf(W[(size_t)(k0 + 7) * 128]);
            *(ushort4*)&Wt1[c * 128 + k0]     = a;
            *(ushort4*)&Wt1[c * 128 + k0 + 4] = b;
        } else if (tid < 6144) {        // Wt2: 128 cols x 16 chunks of 8
            int t = tid - 4096;
            int c = t >> 4, k0 = (t & 15) << 3;
            const float* W = (c < 64) ? (Ws2 + c) : (Wn2 + (c - 64));
            ushort4 a, b;
            a.x = f2bf(W[(size_t)(k0 + 0) * 64]); a.y = f2bf(W[(size_t)(k0 + 1) * 64]);
            a.z = f2bf(W[(size_t)(k0 + 2) * 64]); a.w = f2bf(W[(size_t)(k0 + 3) * 64]);
            b.x = f2bf(W[(size_t)(k0 + 4) * 64]); b.y = f2bf(W[(size_t)(k0 + 5) * 64]);
            b.z = f2bf(W[(size_t)(k0 + 6) * 64]); b.w = f2bf(W[(size_t)(k0 + 7) * 64]);
            *(ushort4*)&Wt2[c * 128 + k0]     = a;
            *(ushort4*)&Wt2[c * 128 + k0 + 4] = b;
        }
        return;
    }
    int e = ((int)blockIdx.x - 24) * 256 + threadIdx.x;
    if (e < E) rank[e] = (unsigned short)atomicAdd(&cnt[dst[e]], 1);
}

// ===========================================================================
// Scan step 1: per-256-chunk sums.
// ===========================================================================
__global__ void block_sums_kernel(const int* __restrict__ cnt, int* __restrict__ partial, int N) {
    __shared__ int s[256];
    int i = blockIdx.x * 256 + threadIdx.x;
    s[threadIdx.x] = (i < N) ? cnt[i] : 0;
    __syncthreads();
    for (int o = 128; o > 0; o >>= 1) {
        if (threadIdx.x < o) s[threadIdx.x] += s[threadIdx.x + o];
        __syncthreads();
    }
    if (threadIdx.x == 0) partial[blockIdx.x] = s[0];
}

// ===========================================================================
// Scan step 2: each block reduces partial[0..blockIdx) itself (NB<=256),
// then in-block exclusive scan of its cnt chunk -> row_ptr.
// ===========================================================================
__global__ void scan_chunks_kernel(const int* __restrict__ cnt, const int* __restrict__ partial,
                                   int* __restrict__ row_ptr, int N, int NB) {
    __shared__ int s[256];
    const int t = threadIdx.x;
    // base = sum of partial[0..blockIdx.x)
    s[t] = (t < NB && t < (int)blockIdx.x) ? partial[t] : 0;
    __syncthreads();
    for (int o = 128; o > 0; o >>= 1) {
        if (t < o) s[t] += s[t + o];
        __syncthreads();
    }
    const int base = s[0];
    __syncthreads();
    // in-block inclusive scan of this chunk
    int i = blockIdx.x * 256 + t;
    int v = (i < N) ? cnt[i] : 0;
    s[t] = v;
    __syncthreads();
    for (int o = 1; o < 256; o <<= 1) {
        int tv = (t >= o) ? s[t - o] : 0;
        __syncthreads();
        s[t] += tv;
        __syncthreads();
    }
    int incl = s[t];
    if (i < N) row_ptr[i] = base + incl - v;
    if (i == N - 1) row_ptr[N] = base + incl;
}

// ===========================================================================
// Fused layer-1: blocks [0, FB) = non-atomic CSR scatter; blocks [FB, FB+NT)
// = one 64-node MFMA dual-GEMM tile (weights from pre-transposed Wt1).
// GEMM: hsb[n] = bf16(x[n]@Ws1 + b1) ; t[n] = bf16(x[n]@Wn1).
// ===========================================================================
__global__ __launch_bounds__(256) void gemm1_fill_kernel(
        const float* __restrict__ x,
        const unsigned short* __restrict__ Wt,   // [256][128] bf16
        const float* __restrict__ bias,
        unsigned short* __restrict__ hsb,
        unsigned short* __restrict__ t,
        int N, int FB,
        const int* __restrict__ src,
        const int* __restrict__ dst,
        const int* __restrict__ row_ptr,
        const unsigned short* __restrict__ rank,
        unsigned short* __restrict__ col_src,
        int E) {
    constexpr int DOUT = HID_DIM;
    constexpr int K   = 128;
    constexpr int MT  = 64;
    constexpr int SL  = 2 * DOUT / 4;   // 64 cols per wave
    constexpr int TN  = SL / 16;        // 4
    constexpr int TM  = MT / 16;        // 4
    constexpr int KS  = K / 32;         // 4
    constexpr int LDA = K + 8;

    __shared__ unsigned short sA[MT][LDA];

    const int tid = threadIdx.x;

    if ((int)blockIdx.x < FB) {
        int base = (int)blockIdx.x * 1024;
        #pragma unroll
        for (int k = 0; k < 4; ++k) {
            int e = base + k * 256 + tid;
            if (e < E) {
                int d = dst[e];
                col_src[row_ptr[d] + (int)rank[e]] = (unsigned short)src[e];
            }
        }
        return;
    }

    const int w   = tid >> 6;
    const int l   = tid & 63;
    const int l16 = l & 15;
    const int lhi = l >> 4;
    const int n0  = ((int)blockIdx.x - FB) * MT;

    // ---- stage A tile: 64 x 128 fp32 -> bf16 in LDS ----
    #pragma unroll
    for (int it = 0; it < 8; ++it) {
        int flat = it * 256 + tid;
        int r  = flat >> 5;
        int c4 = flat & 31;
        float4 v = {0, 0, 0, 0};
        if (n0 + r < N) v = *(const float4*)&x[(size_t)(n0 + r) * K + c4 * 4];
        ushort4 p;
        p.x = f2bf(v.x); p.y = f2bf(v.y); p.z = f2bf(v.z); p.w = f2bf(v.w);
        *(ushort4*)&sA[r][c4 * 4] = p;
    }

    // ---- weight fragments: one 16B load each ----
    bf16x8 breg[TN][KS];
    float  bval[TN];
    #pragma unroll
    for (int tn = 0; tn < TN; ++tn) {
        const int c = w * SL + tn * 16 + l16;
        bval[tn] = (c < DOUT) ? bias[c] : 0.0f;
        #pragma unroll
        for (int ks = 0; ks < KS; ++ks)
            breg[tn][ks] = *(const bf16x8*)&Wt[c * 128 + ks * 32 + lhi * 8];
    }
    __syncthreads();

    f32x4 acc[TN][TM];
    #pragma unroll
    for (int tn = 0; tn < TN; ++tn)
        #pragma unroll
        for (int tm = 0; tm < TM; ++tm)
            acc[tn][tm] = (f32x4){0.0f, 0.0f, 0.0f, 0.0f};

    #pragma unroll
    for (int ks = 0; ks < KS; ++ks) {
        bf16x8 a[TM];
        #pragma unroll
        for (int tm = 0; tm < TM; ++tm)
            a[tm] = *(const bf16x8*)&sA[tm * 16 + l16][ks * 32 + lhi * 8];
        #pragma unroll
        for (int tn = 0; tn < TN; ++tn)
            #pragma unroll
            for (int tm = 0; tm < TM; ++tm)
                acc[tn][tm] = __builtin_amdgcn_mfma_f32_16x16x32_bf16(
                    a[tm], breg[tn][ks], acc[tn][tm], 0, 0, 0);
    }

    // ---- epilogue: C/D layout col=lane&15, row=(lane>>4)*4+r ----
    #pragma unroll
    for (int tn = 0; tn < TN; ++tn) {
        const int c = w * SL + tn * 16 + l16;
        const bool self = (c < DOUT);
        const int cc = self ? c : c - DOUT;
        #pragma unroll
        for (int tm = 0; tm < TM; ++tm) {
            #pragma unroll
            for (int r = 0; r < 4; ++r) {
                const int n = n0 + tm * 16 + lhi * 4 + r;
                if (n < N) {
                    const unsigned short v = f2bf(acc[tn][tm][r] + bval[tn]);
                    if (self) hsb[(size_t)n * DOUT + cc] = v;
                    else      t  [(size_t)n * DOUT + cc] = v;
                }
            }
        }
    }
}

// ===========================================================================
// Gather-mean layer 1 (D=128): one 64-lane wave per node.
// out (bf16) = relu(base(bf16) + mean t[neighbors])
// ===========================================================================
__global__ void gather_mean128_kernel(const unsigned short* __restrict__ t,
                                      const unsigned short* __restrict__ base,
                                      const int* __restrict__ row_ptr,
                                      const unsigned short* __restrict__ col_src,
                                      unsigned short* __restrict__ out, int N) {
    int node = (blockIdx.x * blockDim.x + threadIdx.x) >> 6;
    int lane = threadIdx.x & 63;
    if (node >= N) return;
    const int beg = row_ptr[node], end = row_ptr[node + 1];
    const float rdeg = 1.0f / fmaxf((float)(end - beg), 1.0f);
    const int off = lane * 2;

    float a0x = 0, a0y = 0, a1x = 0, a1y = 0, a2x = 0, a2y = 0, a3x = 0, a3y = 0;
    int i = beg;
    for (; i + 4 <= end; i += 4) {
        int s0 = col_src[i], s1 = col_src[i + 1], s2 = col_src[i + 2], s3 = col_src[i + 3];
        unsigned int u0 = *(const unsigned int*)&t[(size_t)s0 * 128 + off];
        unsigned int u1 = *(const unsigned int*)&t[(size_t)s1 * 128 + off];
        unsigned int u2 = *(const unsigned int*)&t[(size_t)s2 * 128 + off];
        unsigned int u3 = *(const unsigned int*)&t[(size_t)s3 * 128 + off];
        a0x += bflo(u0); a0y += bfhi(u0);
        a1x += bflo(u1); a1y += bfhi(u1);
        a2x += bflo(u2); a2y += bfhi(u2);
        a3x += bflo(u3); a3y += bfhi(u3);
    }
    for (; i < end; ++i) {
        unsigned int u = *(const unsigned int*)&t[(size_t)col_src[i] * 128 + off];
        a0x += bflo(u); a0y += bfhi(u);
    }
    float ax = (a0x + a1x) + (a2x + a3x);
    float ay = (a0y + a1y) + (a2y + a3y);
    unsigned int ub = *(const unsigned int*)&base[(size_t)node * 128 + off];
    float ox = fmaxf(bflo(ub) + ax * rdeg, 0.0f);
    float oy = fmaxf(bfhi(ub) + ay * rdeg, 0.0f);
    *(unsigned int*)&out[(size_t)node * 128 + off] = pack2(ox, oy);
}

// ===========================================================================
// Layer-2 MFMA dual GEMM, bf16 input (h1), weights from Wt2; bf16 outputs.
// ===========================================================================
__global__ __launch_bounds__(256) void gemm2_kernel(
        const unsigned short* __restrict__ x,   // h1 bf16 [N][128]
        const unsigned short* __restrict__ Wt,  // [128][128] bf16
        const float* __restrict__ bias,
        unsigned short* __restrict__ hsb2,
        unsigned short* __restrict__ t2,
        int N) {
    constexpr int DOUT = OUT_DIM;
    constexpr int K   = 128;
    constexpr int MT  = 64;
    constexpr int SL  = 2 * DOUT / 4;   // 32
    constexpr int TN  = SL / 16;        // 2
    constexpr int TM  = MT / 16;        // 4
    constexpr int KS  = K / 32;         // 4
    constexpr int LDA = K + 8;

    __shared__ unsigned short sA[MT][LDA];

    const int tid = threadIdx.x;
    const int w   = tid >> 6;
    const int l   = tid & 63;
    const int l16 = l & 15;
    const int lhi = l >> 4;
    const int n0  = (int)blockIdx.x * MT;

    // ---- stage A tile: 64 x 128 bf16 copy ----
    #pragma unroll
    for (int it = 0; it < 4; ++it) {
        int flat = it * 256 + tid;
        int r  = flat >> 4;
        int c8 = flat & 15;
        uint4 v = {0, 0, 0, 0};
        if (n0 + r < N) v = *(const uint4*)&x[(size_t)(n0 + r) * K + c8 * 8];
        *(uint4*)&sA[r][c8 * 8] = v;
    }

    bf16x8 breg[TN][KS];
    float  bval[TN];
    #pragma unroll
    for (int tn = 0; tn < TN; ++tn) {
        const int c = w * SL + tn * 16 + l16;
        bval[tn] = (c < DOUT) ? bias[c] : 0.0f;
        #pragma unroll
        for (int ks = 0; ks < KS; ++ks)
            breg[tn][ks] = *(const bf16x8*)&Wt[c * 128 + ks * 32 + lhi * 8];
    }
    __syncthreads();

    f32x4 acc[TN][TM];
    #pragma unroll
    for (int tn = 0; tn < TN; ++tn)
        #pragma unroll
        for (int tm = 0; tm < TM; ++tm)
            acc[tn][tm] = (f32x4){0.0f, 0.0f, 0.0f, 0.0f};

    #pragma unroll
    for (int ks = 0; ks < KS; ++ks) {
        bf16x8 a[TM];
        #pragma unroll
        for (int tm = 0; tm < TM; ++tm)
            a[tm] = *(const bf16x8*)&sA[tm * 16 + l16][ks * 32 + lhi * 8];
        #pragma unroll
        for (int tn = 0; tn < TN; ++tn)
            #pragma unroll
            for (int tm = 0; tm < TM; ++tm)
                acc[tn][tm] = __builtin_amdgcn_mfma_f32_16x16x32_bf16(
                    a[tm], breg[tn][ks], acc[tn][tm], 0, 0, 0);
    }

    #pragma unroll
    for (int tn = 0; tn < TN; ++tn) {
        const int c = w * SL + tn * 16 + l16;
        const bool self = (c < DOUT);
        const int cc = self ? c : c - DOUT;
        #pragma unroll
        for (int tm = 0; tm < TM; ++tm) {
            #pragma unroll
            for (int r = 0; r < 4; ++r) {
                const int n = n0 + tm * 16 + lhi * 4 + r;
                if (n < N) {
                    const unsigned short v = f2bf(acc[tn][tm][r] + bval[tn]);
                    if (self) hsb2[(size_t)n * DOUT + cc] = v;
                    else      t2  [(size_t)n * DOUT + cc] = v;
                }
            }
        }
    }
}

// ===========================================================================
// Gather-mean layer 2 (D=64): 32 lanes per node (2 nodes/wave), bf16 base/out.
// ===========================================================================
__global__ void gather_mean64_kernel(const unsigned short* __restrict__ t,
                                     const unsigned short* __restrict__ base,
                                     const int* __restrict__ row_ptr,
                                     const unsigned short* __restrict__ col_src,
                                     unsigned short* __restrict__ out, int N) {
    int tid  = blockIdx.x * blockDim.x + threadIdx.x;
    int node = (tid >> 6) * 2 + ((tid >> 5) & 1);
    int m    = tid & 31;
    if (node >= N) return;
    const int beg = row_ptr[node], end = row_ptr[node + 1];
    const float rdeg = 1.0f / fmaxf((float)(end - beg), 1.0f);
    const int off = m * 2;

    float a0x = 0, a0y = 0, a1x = 0, a1y = 0, a2x = 0, a2y = 0, a3x = 0, a3y = 0;
    int i = beg;
    for (; i + 4 <= end; i += 4) {
        int s0 = col_src[i], s1 = col_src[i + 1], s2 = col_src[i + 2], s3 = col_src[i + 3];
        unsigned int u0 = *(const unsigned int*)&t[(size_t)s0 * 64 + off];
        unsigned int u1 = *(const unsigned int*)&t[(size_t)s1 * 64 + off];
        unsigned int u2 = *(const unsigned int*)&t[(size_t)s2 * 64 + off];
        unsigned int u3 = *(const unsigned int*)&t[(size_t)s3 * 64 + off];
        a0x += bflo(u0); a0y += bfhi(u0);
        a1x += bflo(u1); a1y += bfhi(u1);
        a2x += bflo(u2); a2y += bfhi(u2);
        a3x += bflo(u3); a3y += bfhi(u3);
    }
    for (; i < end; ++i) {
        unsigned int u = *(const unsigned int*)&t[(size_t)col_src[i] * 64 + off];
        a0x += bflo(u); a0y += bfhi(u);
    }
    float ax = (a0x + a1x) + (a2x + a3x);
    float ay = (a0y + a1y) + (a2y + a3y);
    unsigned int ub = *(const unsigned int*)&base[(size_t)node * 64 + off];
    *(unsigned int*)&out[(size_t)node * 64 + off] =
        pack2(bflo(ub) + ax * rdeg, bfhi(ub) + ay * rdeg);
}

// ===========================================================================
// Edge dot on bf16 h (D=64, 128B rows): 4 lanes/edge, 2x uint4 per row per
// lane (4 independent 16B gathers -> better MLP), 2-step shfl reduce.
// ===========================================================================
__global__ void edge_dot_kernel(const unsigned short* __restrict__ h,
                                const int* __restrict__ src,
                                const int* __restrict__ dst,
                                const int* __restrict__ nsrc,
                                const int* __restrict__ ndst,
                                float* __restrict__ out,
                                int E) {
    int tid = blockIdx.x * blockDim.x + threadIdx.x;
    int eg = tid >> 2;
    int l  = tid & 3;
    if (eg >= 2 * E) return;
    int s, t;
    if (eg < E) { s = src[eg];      t = dst[eg]; }
    else        { s = nsrc[eg - E]; t = ndst[eg - E]; }
    const uint4* pa = (const uint4*)&h[(size_t)s * OUT_DIM + l * 16];
    const uint4* pb = (const uint4*)&h[(size_t)t * OUT_DIM + l * 16];
    uint4 a0 = pa[0], a1 = pa[1];
    uint4 b0 = pb[0], b1 = pb[1];
    float v = dot8(a0, b0) + dot8(a1, b1);
    v += __shfl_xor(v, 2, 4);
    v += __shfl_xor(v, 1, 4);
    if (l == 0) out[eg] = v;
}

extern "C" void kernel_launch(void* const* d_in, const int* in_sizes, int n_in,
                              void* d_out, int out_size, void* d_ws, size_t ws_size,
                              hipStream_t stream) {
    const float* feat = (const float*)d_in[0];
    const float* Ws1  = (const float*)d_in[1];
    const float* Wn1  = (const float*)d_in[2];
    const float* b1   = (const float*)d_in[3];
    const float* Ws2  = (const float*)d_in[4];
    const float* Wn2  = (const float*)d_in[5];
    const float* b2   = (const float*)d_in[6];
    const int* src  = (const int*)d_in[7];
    const int* dst  = (const int*)d_in[8];
    const int* nsrc = (const int*)d_in[9];
    const int* ndst = (const int*)d_in[10];
    const int E = in_sizes[7];
    const int N = in_sizes[0] / IN_DIM;
    const int NB = (N + 255) / 256;
    const int NT = (N + 63) / 64;           // MFMA node tiles
    const int FB = (E + 1023) / 1024;       // scatter blocks
    const int HB = (E + 255) / 256;         // hist blocks

    // ---- workspace layout (16B-aligned big arrays first) ----
    char* wsb = (char*)d_ws;
    unsigned short* Wt1  = (unsigned short*)wsb;                         // [256][128]
    unsigned short* Wt2  = Wt1 + 256 * 128;                              // [128][128]
    unsigned short* t1   = Wt2 + 128 * 128;                              // N*128 bf16
    unsigned short* hs1b = t1 + (size_t)N * HID_DIM;                     // N*128 bf16
    unsigned short* h1   = hs1b + (size_t)N * HID_DIM;                   // N*128 bf16
    unsigned short* t2   = h1 + (size_t)N * HID_DIM;                     // N*64 bf16
    unsigned short* hs2b = t2 + (size_t)N * OUT_DIM;                     // N*64 bf16
    unsigned short* h2   = hs2b + (size_t)N * OUT_DIM;                   // N*64 bf16
    int* cnt             = (int*)(h2 + (size_t)N * OUT_DIM);             // N
    int* row_ptr         = cnt + N;                                      // N+1
    int* partial         = row_ptr + N + 1;                              // 256
    unsigned short* rank    = (unsigned short*)(partial + 256);          // E
    unsigned short* col_src = rank + E;                                  // E

    // ---- CSR build + weight transpose (fused) ----
    hipMemsetAsync(cnt, 0, sizeof(int) * (size_t)N, stream);
    wtrans_hist_kernel<<<24 + HB, 256, 0, stream>>>(
        Ws1, Wn1, Ws2, Wn2, Wt1, Wt2, dst, cnt, rank, E);
    block_sums_kernel<<<NB, 256, 0, stream>>>(cnt, partial, N);
    scan_chunks_kernel<<<NB, 256, 0, stream>>>(cnt, partial, row_ptr, N, NB);

    // ---- Layer 1 GEMM (1 tile/block) fused with non-atomic CSR scatter ----
    gemm1_fill_kernel<<<FB + NT, 256, 0, stream>>>(
        feat, Wt1, b1, hs1b, t1, N, FB,
        src, dst, row_ptr, rank, col_src, E);

    // ---- Layer 1 gather-mean + relu -> h1 (bf16; one wave per node) ----
    gather_mean128_kernel<<<(N * 64 + 255) / 256, 256, 0, stream>>>(
        t1, hs1b, row_ptr, col_src, h1, N);

    // ---- Layer 2 GEMM (bf16 input) ----
    gemm2_kernel<<<NT, 256, 0, stream>>>(
        h1, Wt2, b2, hs2b, t2, N);

    // ---- Layer 2 gather-mean -> h2 (bf16) ----
    {
        int waves = (N + 1) / 2;
        gather_mean64_kernel<<<(waves * 64 + 255) / 256, 256, 0, stream>>>(
            t2, hs2b, row_ptr, col_src, h2, N);
    }

    // ---- Edge dots (4 lanes/edge) ----
    {
        int total = 2 * E * 4;
        edge_dot_kernel<<<(total + 255) / 256, 256, 0, stream>>>(
            h2, src, dst, nsrc, ndst, (float*)d_out, E);
    }
}

// Round 10
// 182.603 us; speedup vs baseline: 1.6229x; 1.0055x over previous
//
#include <hip/hip_runtime.h>

#define IN_DIM 128
#define HID_DIM 128
#define OUT_DIM 64

typedef short bf16x8 __attribute__((ext_vector_type(8)));   // 8 bf16 (4 VGPRs)
typedef float f32x4  __attribute__((ext_vector_type(4)));   // 4 fp32 acc

// ---- bf16 helpers (storage-only; math in fp32) ----
__device__ inline float bflo(unsigned int u) { return __uint_as_float(u << 16); }
__device__ inline float bfhi(unsigned int u) { return __uint_as_float(u & 0xffff0000u); }
__device__ inline unsigned short f2bf(float f) {
    unsigned int b = __float_as_uint(f);
    return (unsigned short)((b + 0x7FFFu + ((b >> 16) & 1u)) >> 16);  // RNE
}
__device__ inline unsigned int pack2(float a, float b) {
    return (unsigned int)f2bf(a) | ((unsigned int)f2bf(b) << 16);
}
__device__ inline float dot8(uint4 a, uint4 b) {
    return bflo(a.x) * bflo(b.x) + bfhi(a.x) * bfhi(b.x)
         + bflo(a.y) * bflo(b.y) + bfhi(a.y) * bfhi(b.y)
         + bflo(a.z) * bflo(b.z) + bfhi(a.z) * bfhi(b.z)
         + bflo(a.w) * bflo(b.w) + bfhi(a.w) * bfhi(b.w);
}

// ===========================================================================
// Zero cnt (custom; rocclr fillBuffer was 42us for 200KB — 0.06% HBM util).
// ===========================================================================
__global__ void zero_cnt_kernel(uint4* __restrict__ p, int n4) {
    int i = blockIdx.x * blockDim.x + threadIdx.x;
    if (i < n4) p[i] = (uint4){0, 0, 0, 0};
}

// ===========================================================================
// Fused: blocks [0,24) transpose+convert weights (Wt1 [256][128], Wt2 [128][128]
// bf16); blocks [24, ...) do histogram + per-edge rank (atomic return).
// ===========================================================================
__global__ void wtrans_hist_kernel(const float* __restrict__ Ws1, const float* __restrict__ Wn1,
                                   const float* __restrict__ Ws2, const float* __restrict__ Wn2,
                                   unsigned short* __restrict__ Wt1, unsigned short* __restrict__ Wt2,
                                   const int* __restrict__ dst, int* __restrict__ cnt,
                                   unsigned short* __restrict__ rank, int E) {
    if ((int)blockIdx.x < 24) {
        int tid = (int)blockIdx.x * 256 + threadIdx.x;
        if (tid < 4096) {               // Wt1: 256 cols x 16 chunks of 8
            int c = tid >> 4, k0 = (tid & 15) << 3;
            const float* W = (c < 128) ? (Ws1 + c) : (Wn1 + (c - 128));
            ushort4 a, b;
            a.x = f2bf(W[(size_t)(k0 + 0) * 128]); a.y = f2bf(W[(size_t)(k0 + 1) * 128]);
            a.z = f2bf(W[(size_t)(k0 + 2) * 128]); a.w = f2bf(W[(size_t)(k0 + 3) * 128]);
            b.x = f2bf(W[(size_t)(k0 + 4) * 128]); b.y = f2bf(W[(size_t)(k0 + 5) * 128]);
            b.z = f2bf(W[(size_t)(k0 + 6) * 128]); b.w = f2bf(W[(size_t)(k0 + 7) * 128]);
            *(ushort4*)&Wt1[c * 128 + k0]     = a;
            *(ushort4*)&Wt1[c * 128 + k0 + 4] = b;
        } else if (tid < 6144) {        // Wt2: 128 cols x 16 chunks of 8
            int t = tid - 4096;
            int c = t >> 4, k0 = (t & 15) << 3;
            const float* W = (c < 64) ? (Ws2 + c) : (Wn2 + (c - 64));
            ushort4 a, b;
            a.x = f2bf(W[(size_t)(k0 + 0) * 64]); a.y = f2bf(W[(size_t)(k0 + 1) * 64]);
            a.z = f2bf(W[(size_t)(k0 + 2) * 64]); a.w = f2bf(W[(size_t)(k0 + 3) * 64]);
            b.x = f2bf(W[(size_t)(k0 + 4) * 64]); b.y = f2bf(W[(size_t)(k0 + 5) * 64]);
            b.z = f2bf(W[(size_t)(k0 + 6) * 64]); b.w = f2bf(W[(size_t)(k0 + 7) * 64]);
            *(ushort4*)&Wt2[c * 128 + k0]     = a;
            *(ushort4*)&Wt2[c * 128 + k0 + 4] = b;
        }
        return;
    }
    int e = ((int)blockIdx.x - 24) * 256 + threadIdx.x;
    if (e < E) rank[e] = (unsigned short)atomicAdd(&cnt[dst[e]], 1);
}

// ===========================================================================
// Scan step 1: per-256-chunk sums.
// ===========================================================================
__global__ void block_sums_kernel(const int* __restrict__ cnt, int* __restrict__ partial, int N) {
    __shared__ int s[256];
    int i = blockIdx.x * 256 + threadIdx.x;
    s[threadIdx.x] = (i < N) ? cnt[i] : 0;
    __syncthreads();
    for (int o = 128; o > 0; o >>= 1) {
        if (threadIdx.x < o) s[threadIdx.x] += s[threadIdx.x + o];
        __syncthreads();
    }
    if (threadIdx.x == 0) partial[blockIdx.x] = s[0];
}

// ===========================================================================
// Scan step 2: each block reduces partial[0..blockIdx) itself (NB<=256),
// then in-block exclusive scan of its cnt chunk -> row_ptr.
// ===========================================================================
__global__ void scan_chunks_kernel(const int* __restrict__ cnt, const int* __restrict__ partial,
                                   int* __restrict__ row_ptr, int N, int NB) {
    __shared__ int s[256];
    const int t = threadIdx.x;
    s[t] = (t < NB && t < (int)blockIdx.x) ? partial[t] : 0;
    __syncthreads();
    for (int o = 128; o > 0; o >>= 1) {
        if (t < o) s[t] += s[t + o];
        __syncthreads();
    }
    const int base = s[0];
    __syncthreads();
    int i = blockIdx.x * 256 + t;
    int v = (i < N) ? cnt[i] : 0;
    s[t] = v;
    __syncthreads();
    for (int o = 1; o < 256; o <<= 1) {
        int tv = (t >= o) ? s[t - o] : 0;
        __syncthreads();
        s[t] += tv;
        __syncthreads();
    }
    int incl = s[t];
    if (i < N) row_ptr[i] = base + incl - v;
    if (i == N - 1) row_ptr[N] = base + incl;
}

// ===========================================================================
// Fused layer-1: blocks [0, FB) = non-atomic CSR scatter; blocks [FB, FB+NT)
// = one 64-node MFMA dual-GEMM tile (weights from pre-transposed Wt1).
// GEMM: hsb[n] = bf16(x[n]@Ws1 + b1) ; t[n] = bf16(x[n]@Wn1).
// ===========================================================================
__global__ __launch_bounds__(256) void gemm1_fill_kernel(
        const float* __restrict__ x,
        const unsigned short* __restrict__ Wt,   // [256][128] bf16
        const float* __restrict__ bias,
        unsigned short* __restrict__ hsb,
        unsigned short* __restrict__ t,
        int N, int FB,
        const int* __restrict__ src,
        const int* __restrict__ dst,
        const int* __restrict__ row_ptr,
        const unsigned short* __restrict__ rank,
        unsigned short* __restrict__ col_src,
        int E) {
    constexpr int DOUT = HID_DIM;
    constexpr int K   = 128;
    constexpr int MT  = 64;
    constexpr int SL  = 2 * DOUT / 4;   // 64 cols per wave
    constexpr int TN  = SL / 16;        // 4
    constexpr int TM  = MT / 16;        // 4
    constexpr int KS  = K / 32;         // 4
    constexpr int LDA = K + 8;

    __shared__ unsigned short sA[MT][LDA];

    const int tid = threadIdx.x;

    if ((int)blockIdx.x < FB) {
        int base = (int)blockIdx.x * 1024;
        #pragma unroll
        for (int k = 0; k < 4; ++k) {
            int e = base + k * 256 + tid;
            if (e < E) {
                int d = dst[e];
                col_src[row_ptr[d] + (int)rank[e]] = (unsigned short)src[e];
            }
        }
        return;
    }

    const int w   = tid >> 6;
    const int l   = tid & 63;
    const int l16 = l & 15;
    const int lhi = l >> 4;
    const int n0  = ((int)blockIdx.x - FB) * MT;

    // ---- stage A tile: 64 x 128 fp32 -> bf16 in LDS ----
    #pragma unroll
    for (int it = 0; it < 8; ++it) {
        int flat = it * 256 + tid;
        int r  = flat >> 5;
        int c4 = flat & 31;
        float4 v = {0, 0, 0, 0};
        if (n0 + r < N) v = *(const float4*)&x[(size_t)(n0 + r) * K + c4 * 4];
        ushort4 p;
        p.x = f2bf(v.x); p.y = f2bf(v.y); p.z = f2bf(v.z); p.w = f2bf(v.w);
        *(ushort4*)&sA[r][c4 * 4] = p;
    }

    // ---- weight fragments: one 16B load each ----
    bf16x8 breg[TN][KS];
    float  bval[TN];
    #pragma unroll
    for (int tn = 0; tn < TN; ++tn) {
        const int c = w * SL + tn * 16 + l16;
        bval[tn] = (c < DOUT) ? bias[c] : 0.0f;
        #pragma unroll
        for (int ks = 0; ks < KS; ++ks)
            breg[tn][ks] = *(const bf16x8*)&Wt[c * 128 + ks * 32 + lhi * 8];
    }
    __syncthreads();

    f32x4 acc[TN][TM];
    #pragma unroll
    for (int tn = 0; tn < TN; ++tn)
        #pragma unroll
        for (int tm = 0; tm < TM; ++tm)
            acc[tn][tm] = (f32x4){0.0f, 0.0f, 0.0f, 0.0f};

    #pragma unroll
    for (int ks = 0; ks < KS; ++ks) {
        bf16x8 a[TM];
        #pragma unroll
        for (int tm = 0; tm < TM; ++tm)
            a[tm] = *(const bf16x8*)&sA[tm * 16 + l16][ks * 32 + lhi * 8];
        #pragma unroll
        for (int tn = 0; tn < TN; ++tn)
            #pragma unroll
            for (int tm = 0; tm < TM; ++tm)
                acc[tn][tm] = __builtin_amdgcn_mfma_f32_16x16x32_bf16(
                    a[tm], breg[tn][ks], acc[tn][tm], 0, 0, 0);
    }

    // ---- epilogue: C/D layout col=lane&15, row=(lane>>4)*4+r ----
    #pragma unroll
    for (int tn = 0; tn < TN; ++tn) {
        const int c = w * SL + tn * 16 + l16;
        const bool self = (c < DOUT);
        const int cc = self ? c : c - DOUT;
        #pragma unroll
        for (int tm = 0; tm < TM; ++tm) {
            #pragma unroll
            for (int r = 0; r < 4; ++r) {
                const int n = n0 + tm * 16 + lhi * 4 + r;
                if (n < N) {
                    const unsigned short v = f2bf(acc[tn][tm][r] + bval[tn]);
                    if (self) hsb[(size_t)n * DOUT + cc] = v;
                    else      t  [(size_t)n * DOUT + cc] = v;
                }
            }
        }
    }
}

// ===========================================================================
// Gather-mean layer 1 (D=128): one 64-lane wave per node.
// out (bf16) = relu(base(bf16) + mean t[neighbors])
// ===========================================================================
__global__ void gather_mean128_kernel(const unsigned short* __restrict__ t,
                                      const unsigned short* __restrict__ base,
                                      const int* __restrict__ row_ptr,
                                      const unsigned short* __restrict__ col_src,
                                      unsigned short* __restrict__ out, int N) {
    int node = (blockIdx.x * blockDim.x + threadIdx.x) >> 6;
    int lane = threadIdx.x & 63;
    if (node >= N) return;
    const int beg = row_ptr[node], end = row_ptr[node + 1];
    const float rdeg = 1.0f / fmaxf((float)(end - beg), 1.0f);
    const int off = lane * 2;

    float a0x = 0, a0y = 0, a1x = 0, a1y = 0, a2x = 0, a2y = 0, a3x = 0, a3y = 0;
    int i = beg;
    for (; i + 4 <= end; i += 4) {
        int s0 = col_src[i], s1 = col_src[i + 1], s2 = col_src[i + 2], s3 = col_src[i + 3];
        unsigned int u0 = *(const unsigned int*)&t[(size_t)s0 * 128 + off];
        unsigned int u1 = *(const unsigned int*)&t[(size_t)s1 * 128 + off];
        unsigned int u2 = *(const unsigned int*)&t[(size_t)s2 * 128 + off];
        unsigned int u3 = *(const unsigned int*)&t[(size_t)s3 * 128 + off];
        a0x += bflo(u0); a0y += bfhi(u0);
        a1x += bflo(u1); a1y += bfhi(u1);
        a2x += bflo(u2); a2y += bfhi(u2);
        a3x += bflo(u3); a3y += bfhi(u3);
    }
    for (; i < end; ++i) {
        unsigned int u = *(const unsigned int*)&t[(size_t)col_src[i] * 128 + off];
        a0x += bflo(u); a0y += bfhi(u);
    }
    float ax = (a0x + a1x) + (a2x + a3x);
    float ay = (a0y + a1y) + (a2y + a3y);
    unsigned int ub = *(const unsigned int*)&base[(size_t)node * 128 + off];
    float ox = fmaxf(bflo(ub) + ax * rdeg, 0.0f);
    float oy = fmaxf(bfhi(ub) + ay * rdeg, 0.0f);
    *(unsigned int*)&out[(size_t)node * 128 + off] = pack2(ox, oy);
}

// ===========================================================================
// Layer-2 MFMA dual GEMM, bf16 input (h1), weights from Wt2; bf16 outputs.
// ===========================================================================
__global__ __launch_bounds__(256) void gemm2_kernel(
        const unsigned short* __restrict__ x,   // h1 bf16 [N][128]
        const unsigned short* __restrict__ Wt,  // [128][128] bf16
        const float* __restrict__ bias,
        unsigned short* __restrict__ hsb2,
        unsigned short* __restrict__ t2,
        int N) {
    constexpr int DOUT = OUT_DIM;
    constexpr int K   = 128;
    constexpr int MT  = 64;
    constexpr int SL  = 2 * DOUT / 4;   // 32
    constexpr int TN  = SL / 16;        // 2
    constexpr int TM  = MT / 16;        // 4
    constexpr int KS  = K / 32;         // 4
    constexpr int LDA = K + 8;

    __shared__ unsigned short sA[MT][LDA];

    const int tid = threadIdx.x;
    const int w   = tid >> 6;
    const int l   = tid & 63;
    const int l16 = l & 15;
    const int lhi = l >> 4;
    const int n0  = (int)blockIdx.x * MT;

    // ---- stage A tile: 64 x 128 bf16 copy ----
    #pragma unroll
    for (int it = 0; it < 4; ++it) {
        int flat = it * 256 + tid;
        int r  = flat >> 4;
        int c8 = flat & 15;
        uint4 v = {0, 0, 0, 0};
        if (n0 + r < N) v = *(const uint4*)&x[(size_t)(n0 + r) * K + c8 * 8];
        *(uint4*)&sA[r][c8 * 8] = v;
    }

    bf16x8 breg[TN][KS];
    float  bval[TN];
    #pragma unroll
    for (int tn = 0; tn < TN; ++tn) {
        const int c = w * SL + tn * 16 + l16;
        bval[tn] = (c < DOUT) ? bias[c] : 0.0f;
        #pragma unroll
        for (int ks = 0; ks < KS; ++ks)
            breg[tn][ks] = *(const bf16x8*)&Wt[c * 128 + ks * 32 + lhi * 8];
    }
    __syncthreads();

    f32x4 acc[TN][TM];
    #pragma unroll
    for (int tn = 0; tn < TN; ++tn)
        #pragma unroll
        for (int tm = 0; tm < TM; ++tm)
            acc[tn][tm] = (f32x4){0.0f, 0.0f, 0.0f, 0.0f};

    #pragma unroll
    for (int ks = 0; ks < KS; ++ks) {
        bf16x8 a[TM];
        #pragma unroll
        for (int tm = 0; tm < TM; ++tm)
            a[tm] = *(const bf16x8*)&sA[tm * 16 + l16][ks * 32 + lhi * 8];
        #pragma unroll
        for (int tn = 0; tn < TN; ++tn)
            #pragma unroll
            for (int tm = 0; tm < TM; ++tm)
                acc[tn][tm] = __builtin_amdgcn_mfma_f32_16x16x32_bf16(
                    a[tm], breg[tn][ks], acc[tn][tm], 0, 0, 0);
    }

    #pragma unroll
    for (int tn = 0; tn < TN; ++tn) {
        const int c = w * SL + tn * 16 + l16;
        const bool self = (c < DOUT);
        const int cc = self ? c : c - DOUT;
        #pragma unroll
        for (int tm = 0; tm < TM; ++tm) {
            #pragma unroll
            for (int r = 0; r < 4; ++r) {
                const int n = n0 + tm * 16 + lhi * 4 + r;
                if (n < N) {
                    const unsigned short v = f2bf(acc[tn][tm][r] + bval[tn]);
                    if (self) hsb2[(size_t)n * DOUT + cc] = v;
                    else      t2  [(size_t)n * DOUT + cc] = v;
                }
            }
        }
    }
}

// ===========================================================================
// Gather-mean layer 2 (D=64): 32 lanes per node (2 nodes/wave), bf16 base/out.
// ===========================================================================
__global__ void gather_mean64_kernel(const unsigned short* __restrict__ t,
                                     const unsigned short* __restrict__ base,
                                     const int* __restrict__ row_ptr,
                                     const unsigned short* __restrict__ col_src,
                                     unsigned short* __restrict__ out, int N) {
    int tid  = blockIdx.x * blockDim.x + threadIdx.x;
    int node = (tid >> 6) * 2 + ((tid >> 5) & 1);
    int m    = tid & 31;
    if (node >= N) return;
    const int beg = row_ptr[node], end = row_ptr[node + 1];
    const float rdeg = 1.0f / fmaxf((float)(end - beg), 1.0f);
    const int off = m * 2;

    float a0x = 0, a0y = 0, a1x = 0, a1y = 0, a2x = 0, a2y = 0, a3x = 0, a3y = 0;
    int i = beg;
    for (; i + 4 <= end; i += 4) {
        int s0 = col_src[i], s1 = col_src[i + 1], s2 = col_src[i + 2], s3 = col_src[i + 3];
        unsigned int u0 = *(const unsigned int*)&t[(size_t)s0 * 64 + off];
        unsigned int u1 = *(const unsigned int*)&t[(size_t)s1 * 64 + off];
        unsigned int u2 = *(const unsigned int*)&t[(size_t)s2 * 64 + off];
        unsigned int u3 = *(const unsigned int*)&t[(size_t)s3 * 64 + off];
        a0x += bflo(u0); a0y += bfhi(u0);
        a1x += bflo(u1); a1y += bfhi(u1);
        a2x += bflo(u2); a2y += bfhi(u2);
        a3x += bflo(u3); a3y += bfhi(u3);
    }
    for (; i < end; ++i) {
        unsigned int u = *(const unsigned int*)&t[(size_t)col_src[i] * 64 + off];
        a0x += bflo(u); a0y += bfhi(u);
    }
    float ax = (a0x + a1x) + (a2x + a3x);
    float ay = (a0y + a1y) + (a2y + a3y);
    unsigned int ub = *(const unsigned int*)&base[(size_t)node * 64 + off];
    *(unsigned int*)&out[(size_t)node * 64 + off] =
        pack2(bflo(ub) + ax * rdeg, bfhi(ub) + ay * rdeg);
}

// ===========================================================================
// Edge dot on bf16 h (D=64, 128B rows): 4 lanes/edge, 2x uint4 per row per
// lane (4 independent 16B gathers -> MLP), 2-step shfl reduce.
// ===========================================================================
__global__ void edge_dot_kernel(const unsigned short* __restrict__ h,
                                const int* __restrict__ src,
                                const int* __restrict__ dst,
                                const int* __restrict__ nsrc,
                                const int* __restrict__ ndst,
                                float* __restrict__ out,
                                int E) {
    int tid = blockIdx.x * blockDim.x + threadIdx.x;
    int eg = tid >> 2;
    int l  = tid & 3;
    if (eg >= 2 * E) return;
    int s, t;
    if (eg < E) { s = src[eg];      t = dst[eg]; }
    else        { s = nsrc[eg - E]; t = ndst[eg - E]; }
    const uint4* pa = (const uint4*)&h[(size_t)s * OUT_DIM + l * 16];
    const uint4* pb = (const uint4*)&h[(size_t)t * OUT_DIM + l * 16];
    uint4 a0 = pa[0], a1 = pa[1];
    uint4 b0 = pb[0], b1 = pb[1];
    float v = dot8(a0, b0) + dot8(a1, b1);
    v += __shfl_xor(v, 2, 4);
    v += __shfl_xor(v, 1, 4);
    if (l == 0) out[eg] = v;
}

extern "C" void kernel_launch(void* const* d_in, const int* in_sizes, int n_in,
                              void* d_out, int out_size, void* d_ws, size_t ws_size,
                              hipStream_t stream) {
    const float* feat = (const float*)d_in[0];
    const float* Ws1  = (const float*)d_in[1];
    const float* Wn1  = (const float*)d_in[2];
    const float* b1   = (const float*)d_in[3];
    const float* Ws2  = (const float*)d_in[4];
    const float* Wn2  = (const float*)d_in[5];
    const float* b2   = (const float*)d_in[6];
    const int* src  = (const int*)d_in[7];
    const int* dst  = (const int*)d_in[8];
    const int* nsrc = (const int*)d_in[9];
    const int* ndst = (const int*)d_in[10];
    const int E = in_sizes[7];
    const int N = in_sizes[0] / IN_DIM;
    const int NB = (N + 255) / 256;
    const int NT = (N + 63) / 64;           // MFMA node tiles
    const int FB = (E + 1023) / 1024;       // scatter blocks
    const int HB = (E + 255) / 256;         // hist blocks

    // ---- workspace layout (16B-aligned big arrays first) ----
    char* wsb = (char*)d_ws;
    unsigned short* Wt1  = (unsigned short*)wsb;                         // [256][128]
    unsigned short* Wt2  = Wt1 + 256 * 128;                              // [128][128]
    unsigned short* t1   = Wt2 + 128 * 128;                              // N*128 bf16
    unsigned short* hs1b = t1 + (size_t)N * HID_DIM;                     // N*128 bf16
    unsigned short* h1   = hs1b + (size_t)N * HID_DIM;                   // N*128 bf16
    unsigned short* t2   = h1 + (size_t)N * HID_DIM;                     // N*64 bf16
    unsigned short* hs2b = t2 + (size_t)N * OUT_DIM;                     // N*64 bf16
    unsigned short* h2   = hs2b + (size_t)N * OUT_DIM;                   // N*64 bf16
    int* cnt             = (int*)(h2 + (size_t)N * OUT_DIM);             // N (16B-aligned: preceding bf16 count even)
    int* row_ptr         = cnt + N;                                      // N+1
    int* partial         = row_ptr + N + 1;                              // 256
    unsigned short* rank    = (unsigned short*)(partial + 256);          // E
    unsigned short* col_src = rank + E;                                  // E

    // ---- zero cnt (custom kernel; rocclr fill was 42us) ----
    {
        int n4 = (N + 3) / 4;
        zero_cnt_kernel<<<(n4 + 255) / 256, 256, 0, stream>>>((uint4*)cnt, n4);
    }

    // ---- CSR build + weight transpose (fused) ----
    wtrans_hist_kernel<<<24 + HB, 256, 0, stream>>>(
        Ws1, Wn1, Ws2, Wn2, Wt1, Wt2, dst, cnt, rank, E);
    block_sums_kernel<<<NB, 256, 0, stream>>>(cnt, partial, N);
    scan_chunks_kernel<<<NB, 256, 0, stream>>>(cnt, partial, row_ptr, N, NB);

    // ---- Layer 1 GEMM (1 tile/block) fused with non-atomic CSR scatter ----
    gemm1_fill_kernel<<<FB + NT, 256, 0, stream>>>(
        feat, Wt1, b1, hs1b, t1, N, FB,
        src, dst, row_ptr, rank, col_src, E);

    // ---- Layer 1 gather-mean + relu -> h1 (bf16; one wave per node) ----
    gather_mean128_kernel<<<(N * 64 + 255) / 256, 256, 0, stream>>>(
        t1, hs1b, row_ptr, col_src, h1, N);

    // ---- Layer 2 GEMM (bf16 input) ----
    gemm2_kernel<<<NT, 256, 0, stream>>>(
        h1, Wt2, b2, hs2b, t2, N);

    // ---- Layer 2 gather-mean -> h2 (bf16) ----
    {
        int waves = (N + 1) / 2;
        gather_mean64_kernel<<<(waves * 64 + 255) / 256, 256, 0, stream>>>(
            t2, hs2b, row_ptr, col_src, h2, N);
    }

    // ---- Edge dots (4 lanes/edge) ----
    {
        int total = 2 * E * 4;
        edge_dot_kernel<<<(total + 255) / 256, 256, 0, stream>>>(
            h2, src, dst, nsrc, ndst, (float*)d_out, E);
    }
}